// Round 2
// baseline (1373.744 us; speedup 1.0000x reference)
//
#include <hip/hip_runtime.h>

typedef __bf16 bf16_t;
typedef __bf16 bf16x8 __attribute__((ext_vector_type(8)));
typedef float f32x4 __attribute__((ext_vector_type(4)));
typedef float f32x8 __attribute__((ext_vector_type(8)));

#define NTOKENS 65536   // B*V*T*NTOK = 1*2*4*8192
#define PLANES 8        // b*v*t planes, 8192 tokens each
#define PTOK 8192
#define SWIN 128        // windows per plane

static __device__ __forceinline__ f32x4 mfma16(bf16x8 a, bf16x8 b, f32x4 c) {
    return __builtin_amdgcn_mfma_f32_16x16x32_bf16(a, b, c, 0, 0, 0);
}

// async global->LDS, 16B per lane; lds dest must be wave-uniform base
static __device__ __forceinline__ void gld16(const void* g, void* l) {
    __builtin_amdgcn_global_load_lds(
        (const __attribute__((address_space(1))) void*)g,
        (__attribute__((address_space(3))) void*)l, 16, 0, 0);
}

// bijective XCD-chunk swizzle (nwg must be divisible by 8)
static __device__ __forceinline__ int xcd_swz(int lin, int nwg) {
    return (lin & 7) * (nwg >> 3) + (lin >> 3);
}

// ---- dtype-generic accessors (F32: buffer is float, else bf16) ----
template <bool F32>
static __device__ __forceinline__ f32x8 load8f(const void* p, size_t i) {
    f32x8 r;
    if (F32) {
        const f32x4* q = (const f32x4*)((const float*)p + i);
        f32x4 a = q[0], b = q[1];
#pragma unroll
        for (int j = 0; j < 4; j++) { r[j] = a[j]; r[4 + j] = b[j]; }
    } else {
        bf16x8 v = *(const bf16x8*)((const bf16_t*)p + i);
#pragma unroll
        for (int j = 0; j < 8; j++) r[j] = (float)v[j];
    }
    return r;
}
template <bool F32>
static __device__ __forceinline__ float ld1f(const void* p, size_t i) {
    return F32 ? ((const float*)p)[i] : (float)((const bf16_t*)p)[i];
}
template <bool F32>
static __device__ __forceinline__ void st1f(void* p, size_t i, float v) {
    if (F32) ((float*)p)[i] = v; else ((bf16_t*)p)[i] = (bf16_t)v;
}
static __device__ __forceinline__ bf16x8 cvt8(f32x8 f) {
    bf16x8 w;
#pragma unroll
    for (int j = 0; j < 8; j++) w[j] = (bf16_t)f[j];
    return w;
}

// ---- dtype detector: sample even-indexed uint16s of x ----
__global__ void detect_dtype(const void* x, int* flag) {
    __shared__ int cnt[256];
    int t = threadIdx.x;
    const unsigned short* u = (const unsigned short*)x;
    int c = 0;
    for (int i = t; i < 4096; i += 256) {
        int e = (u[2 * i] >> 7) & 0xFF;
        c += (e >= 64 && e <= 140) ? 1 : 0;
    }
    cnt[t] = c;
    __syncthreads();
    for (int s = 128; s > 0; s >>= 1) {
        if (t < s) cnt[t] += cnt[t + s];
        __syncthreads();
    }
    if (t == 0) flag[0] = (cnt[0] < 3072) ? 1 : 0;
}

// ---- weight transpose+convert (+optional per-k gain): dst[n][k]=g[k]*src[k][n]
__global__ void transpose_conv(const void* src, const void* gain, bf16_t* dst,
                               int K, int N, const int* flag) {
    int idx = blockIdx.x * 256 + threadIdx.x;
    if (idx >= K * N) return;
    int n = idx % N, k = idx / N;
    bool f = *flag;
    float v = f ? ((const float*)src)[(size_t)k * N + n]
                : (float)((const bf16_t*)src)[(size_t)k * N + n];
    if (gain) {
        float g = f ? ((const float*)gain)[k] : (float)((const bf16_t*)gain)[k];
        v *= g;
    }
    dst[(size_t)n * K + k] = (bf16_t)v;
}

// ---- folded bias: out[n] = b[n] + sum_k bln[k]*W[k][n]  (f32 out) ----
__global__ void fold_bias(const void* W, const void* bln, const void* b,
                          float* out, int K, int N, const int* flag) {
    int n = blockIdx.x * 256 + threadIdx.x;
    if (n >= N) return;
    bool f = *flag;
    float s = f ? ((const float*)b)[n] : (float)((const bf16_t*)b)[n];
    for (int k = 0; k < K; k++) {
        float bl = f ? ((const float*)bln)[k] : (float)((const bf16_t*)bln)[k];
        float w  = f ? ((const float*)W)[(size_t)k * N + n]
                     : (float)((const bf16_t*)W)[(size_t)k * N + n];
        s += bl * w;
    }
    out[n] = s;
}

// ---- batch convert small vectors to f32 (one launch) ----
// layout in out: gamma[512] gm[512] gq[512] bq[512] bo[512] b1[1024] b2[512]
__global__ void conv_all(const void* gamma, const void* gm, const void* gq,
                         const void* bq, const void* bo, const void* b1,
                         const void* b2, float* out, const int* flag) {
    int idx = blockIdx.x * 256 + threadIdx.x;  // 0..4095
    bool f = *flag;
    const void* src; int off;
    if      (idx < 512)  { src = gamma; off = idx; }
    else if (idx < 1024) { src = gm;    off = idx - 512; }
    else if (idx < 1536) { src = gq;    off = idx - 1024; }
    else if (idx < 2048) { src = bq;    off = idx - 1536; }
    else if (idx < 2560) { src = bo;    off = idx - 2048; }
    else if (idx < 3584) { src = b1;    off = idx - 2560; }
    else                 { src = b2;    off = idx - 3584; }
    out[idx] = f ? ((const float*)src)[off] : (float)((const bf16_t*)src)[off];
}

// ---- fused LN-normalize: xh[row] = (x[row]-mean)*rstd  (bf16 out) ----
template <bool F32>
static __device__ __forceinline__ void ln_norm_body(const void* x, bf16_t* xh) {
    int wave = threadIdx.x >> 6, lane = threadIdx.x & 63;
    size_t row = (size_t)blockIdx.x * 4 + wave;
    f32x8 f = load8f<F32>(x, row * 512 + lane * 8);
    float s = 0.f, s2 = 0.f;
#pragma unroll
    for (int j = 0; j < 8; j++) { s += f[j]; s2 += f[j] * f[j]; }
#pragma unroll
    for (int off = 32; off > 0; off >>= 1) { s += __shfl_xor(s, off); s2 += __shfl_xor(s2, off); }
    float m = s * (1.f / 512.f);
    float var = s2 * (1.f / 512.f) - m * m;
    float r = 1.f / sqrtf(var + 1e-5f);
    bf16x8 o;
#pragma unroll
    for (int j = 0; j < 8; j++) o[j] = (bf16_t)((f[j] - m) * r);
    *(bf16x8*)(xh + row * 512 + lane * 8) = o;
}
__global__ __launch_bounds__(256) void ln_norm(const void* x, bf16_t* xh,
                                               const int* flag) {
    if (*flag) ln_norm_body<true>(x, xh);
    else       ln_norm_body<false>(x, xh);
}

// ---- pure bf16 GEMM: C = epi(A[M,K] @ Bt[N,K]^T + bias) ----
// EPI 0: +bias   EPI 1: gelu(+bias)   EPI 2: res + gamma*(+bias) (res/C dtype F32)
// A staged via global_load_lds dwordx4 into linear LDS [128][32].
template <int EPI, bool F32>
static __device__ __forceinline__ void gemm_body(
    bf16_t* Al, bf16_t* Bl,
    const bf16_t* A, const bf16_t* Bt, const float* bias, const void* res,
    const float* gamma, void* C, int arow0, int rrow0, int N, int K) {
    int t = threadIdx.x;
    int gx = gridDim.x;
    int nwg = gx * gridDim.y;
    int lin = blockIdx.y * gx + blockIdx.x;
    int s = xcd_swz(lin, nwg);
    int m0 = (s / gx) * 128, n0 = (s % gx) * 128;
    int wave = t >> 6, lane = t & 63, q = lane >> 4, li = lane & 15;
    int wm = (wave >> 1) * 64, wn = (wave & 1) * 64;
    const f32x4 fzero = {0.f, 0.f, 0.f, 0.f};
    f32x4 acc[4][4];
#pragma unroll
    for (int i = 0; i < 4; i++)
#pragma unroll
        for (int n = 0; n < 4; n++) acc[i][n] = fzero;

    // staging geometry: wave w, issue j covers LDS bytes j*4096 + w*1024 + lane*16
    // -> row = j*64 + w*16 + lane/4, col = (lane&3)*8 elems
    int srow = wave * 16 + (lane >> 2);
    int scol = (lane & 3) * 8;
    const bf16_t* ga = A + (size_t)(arow0 + m0 + srow) * K + scol;
    const bf16_t* gb = Bt + (size_t)(n0 + srow) * K + scol;
    bf16_t* la = Al + wave * 512;
    bf16_t* lb = Bl + wave * 512;

    for (int k0 = 0; k0 < K; k0 += 32) {
        gld16(ga + k0, la);
        gld16(ga + (size_t)64 * K + k0, la + 2048);
        gld16(gb + k0, lb);
        gld16(gb + (size_t)64 * K + k0, lb + 2048);
        __syncthreads();
        bf16x8 af[4], bfr[4];
#pragma unroll
        for (int i = 0; i < 4; i++)
            af[i] = *(const bf16x8*)&Al[(wm + 16 * i + li) * 32 + q * 8];
#pragma unroll
        for (int n = 0; n < 4; n++)
            bfr[n] = *(const bf16x8*)&Bl[(wn + 16 * n + li) * 32 + q * 8];
#pragma unroll
        for (int i = 0; i < 4; i++)
#pragma unroll
            for (int n = 0; n < 4; n++) acc[i][n] = mfma16(af[i], bfr[n], acc[i][n]);
        __syncthreads();
    }
    // epilogue: C/D layout col=lane&15, row=q*4+reg
#pragma unroll
    for (int n = 0; n < 4; n++) {
        int col = n0 + wn + 16 * n + li;
        float bv = bias[col];
        float gv = (EPI == 2) ? gamma[col] : 0.f;
#pragma unroll
        for (int i = 0; i < 4; i++) {
            int rowb = m0 + wm + 16 * i + q * 4;
#pragma unroll
            for (int r = 0; r < 4; r++) {
                float v = acc[i][n][r] + bv;
                if (EPI == 1) {
                    float u = v;
                    v = 0.5f * u * (1.f + tanhf(0.7978845608028654f * (u + 0.044715f * u * u * u)));
                }
                if (EPI == 2) {
                    size_t idx = (size_t)(rrow0 + rowb + r) * N + col;
                    v = ld1f<F32>(res, idx) + gv * v;
                    st1f<F32>(C, idx, v);
                } else {
                    ((bf16_t*)C)[(size_t)(rowb + r) * N + col] = (bf16_t)v;
                }
            }
        }
    }
}
template <int EPI>
__global__ __launch_bounds__(256) void gemm_bt(
    const bf16_t* A, const bf16_t* Bt, const float* bias, const void* res,
    const float* gamma, void* C, const int* flag,
    int arow0, int rrow0, int N, int K) {
    __shared__ __align__(16) bf16_t Al[4096];
    __shared__ __align__(16) bf16_t Bl[4096];
    if constexpr (EPI == 2) {
        if (*flag) {
            gemm_body<EPI, true>(Al, Bl, A, Bt, bias, res, gamma, C, arow0, rrow0, N, K);
            return;
        }
    }
    gemm_body<EPI, false>(Al, Bl, A, Bt, bias, res, gamma, C, arow0, rrow0, N, K);
}

// ---- windowed attention (reads pre-normalized bf16 xh; gq/bq f32) ----
// plane >= 0: per-plane mode, grid = 1024, kv/outc plane-local.
// plane < 0 : full-batch mode, grid = 8192, plane from blockIdx, kv/outc global.
__global__ __launch_bounds__(256) void attn_win(
    const bf16_t* xh, const float* gq, const float* bq,
    const bf16_t* kv, bf16_t* outc, int plane) {
    __shared__ __align__(16) char smem[62464];
    bf16_t(*Ql)[72] = (bf16_t(*)[72])smem;            // 64x72  (9216 B)
    bf16_t(*Kl)[72] = (bf16_t(*)[72])(smem + 9216);   // 192x72 (27648 B)
    bf16_t(*Pl)[200] = (bf16_t(*)[200])smem;          // 64x200 overlaps Ql/Kl (dead)
    bf16_t(*Vt)[200] = (bf16_t(*)[200])(smem + 36864);// 64x200, Vt[d][key]

    int blk = xcd_swz(blockIdx.x, gridDim.x);
    bool full = (plane < 0);
    if (full) { plane = blk >> 10; blk &= 1023; }
    int wl = blk >> 3, h = blk & 7;     // window-in-plane, head
    int i = wl;
    int t = threadIdx.x, wave = t >> 6, lane = t & 63, q = lane >> 4, li = lane & 15;
    size_t qg = (size_t)plane * PTOK + (size_t)wl * 64;   // global token base
    size_t ob = full ? qg : (size_t)wl * 64;              // output token base
    const bf16_t* kvp = full ? kv + (size_t)plane * PTOK * 1024 : kv;

    // stage Q (64x64): xh * g_q + b_q
#pragma unroll
    for (int l = t; l < 512; l += 256) {
        int row = l >> 3, seg = l & 7;
        f32x8 xv = load8f<false>(xh, (qg + row) * 512 + h * 64 + seg * 8);
        f32x8 gv = load8f<true>(gq, h * 64 + seg * 8);
        f32x8 bv = load8f<true>(bq, h * 64 + seg * 8);
        f32x8 w;
#pragma unroll
        for (int j = 0; j < 8; j++) w[j] = xv[j] * gv[j] + bv[j];
        *(bf16x8*)&Ql[row][seg * 8] = cvt8(w);
    }
    // stage K (192x64) and V transposed (Vt[d][key]); kvp is plane-local
#pragma unroll
    for (int l = t; l < 1536; l += 256) {
        int row = l >> 3, seg = l & 7;
        int nb = i + (row >> 6) - 1;
        nb = nb < 0 ? 0 : (nb > SWIN - 1 ? SWIN - 1 : nb);
        size_t tok = (size_t)nb * 64 + (row & 63);
        *(bf16x8*)&Kl[row][seg * 8] =
            *(const bf16x8*)&kvp[tok * 1024 + h * 64 + seg * 8];
        bf16x8 vv = *(const bf16x8*)&kvp[tok * 1024 + 512 + h * 64 + seg * 8];
#pragma unroll
        for (int j = 0; j < 8; j++) Vt[seg * 8 + j][row] = vv[j];
    }
    __syncthreads();

    int rm = wave * 16;
    const f32x4 fzero = {0.f, 0.f, 0.f, 0.f};
    f32x4 sc[12];
#pragma unroll
    for (int nt = 0; nt < 12; nt++) sc[nt] = fzero;
#pragma unroll
    for (int ks = 0; ks < 2; ks++) {
        bf16x8 aq = *(const bf16x8*)&Ql[rm + li][ks * 32 + q * 8];
#pragma unroll
        for (int nt = 0; nt < 12; nt++) {
            bf16x8 bk = *(const bf16x8*)&Kl[16 * nt + li][ks * 32 + q * 8];
            sc[nt] = mfma16(aq, bk, sc[nt]);
        }
    }
    // mask + softmax (row q*4+r, key = 16*nt+li)
    bool v0 = (i > 0), v2 = (i < SWIN - 1);
    float mx[4] = {-3e38f, -3e38f, -3e38f, -3e38f};
#pragma unroll
    for (int nt = 0; nt < 12; nt++) {
        bool valid = (nt < 4) ? v0 : ((nt >= 8) ? v2 : true);
#pragma unroll
        for (int r = 0; r < 4; r++) {
            float sv = valid ? sc[nt][r] * 0.125f : -3e38f;
            sc[nt][r] = sv;
            mx[r] = fmaxf(mx[r], sv);
        }
    }
#pragma unroll
    for (int r = 0; r < 4; r++)
#pragma unroll
        for (int msk = 1; msk < 16; msk <<= 1)
            mx[r] = fmaxf(mx[r], __shfl_xor(mx[r], msk));
    float lsum[4] = {0.f, 0.f, 0.f, 0.f};
#pragma unroll
    for (int nt = 0; nt < 12; nt++)
#pragma unroll
        for (int r = 0; r < 4; r++) {
            float e = __expf(sc[nt][r] - mx[r]);
            sc[nt][r] = e;
            lsum[r] += e;
        }
#pragma unroll
    for (int r = 0; r < 4; r++)
#pragma unroll
        for (int msk = 1; msk < 16; msk <<= 1)
            lsum[r] += __shfl_xor(lsum[r], msk);

    __syncthreads();  // all waves done with Ql/Kl before Pl overwrites
#pragma unroll
    for (int nt = 0; nt < 12; nt++)
#pragma unroll
        for (int r = 0; r < 4; r++)
            Pl[rm + q * 4 + r][16 * nt + li] = (bf16_t)sc[nt][r];
    __syncthreads();

    f32x4 o[4];
#pragma unroll
    for (int nt = 0; nt < 4; nt++) o[nt] = fzero;
#pragma unroll
    for (int ks = 0; ks < 6; ks++) {
        bf16x8 ap = *(const bf16x8*)&Pl[rm + li][ks * 32 + q * 8];
#pragma unroll
        for (int nt = 0; nt < 4; nt++) {
            bf16x8 bv = *(const bf16x8*)&Vt[16 * nt + li][ks * 32 + q * 8];
            o[nt] = mfma16(ap, bv, o[nt]);
        }
    }
#pragma unroll
    for (int r = 0; r < 4; r++) {
        float inv = 1.f / lsum[r];
        size_t tokr = ob + rm + q * 4 + r;
#pragma unroll
        for (int nt = 0; nt < 4; nt++)
            outc[tokr * 512 + h * 64 + 16 * nt + li] = (bf16_t)(o[nt][r] * inv);
    }
}

extern "C" void kernel_launch(void* const* d_in, const int* in_sizes, int n_in,
                              void* d_out, int out_size, void* d_ws, size_t ws_size,
                              hipStream_t stream) {
    const void* x      = d_in[0];
    const void* ln_q_g = d_in[1];
    const void* ln_q_b = d_in[2];
    const void* ln_kv_g= d_in[3];
    const void* ln_kv_b= d_in[4];
    const void* W_kv   = d_in[5];
    const void* b_kv   = d_in[6];
    const void* W_o    = d_in[7];
    const void* b_o    = d_in[8];
    const void* gamma  = d_in[9];
    const void* ln_m_g = d_in[10];
    const void* ln_m_b = d_in[11];
    const void* W_emb  = d_in[12];
    const void* b_emb  = d_in[13];
    const void* W1     = d_in[14];
    const void* b1     = d_in[15];
    const void* W2     = d_in[16];
    const void* b2     = d_in[17];
    const void* gm_mlp = d_in[18];
    char* ws = (char*)d_ws;

    // fixed small region
    bf16_t* Wt_kv  = (bf16_t*)(ws);                     // [1024,512]  1 MiB
    bf16_t* Wt_o   = (bf16_t*)(ws + (1u << 20));        // [512,512]
    bf16_t* Wt_emb = (bf16_t*)(ws + 1572864);           // [512,512]
    bf16_t* Wt_1   = (bf16_t*)(ws + (2u << 20));        // [1024,512]
    bf16_t* Wt_2   = (bf16_t*)(ws + (3u << 20));        // [512,1024]
    float*  smallF = (float*)(ws + (4u << 20));         // 16 KiB f32 consts
    float*  bkv_f  = (float*)(ws + (4u << 20) + 16384); // [1024]
    float*  bemb_f = (float*)(ws + (4u << 20) + 20480); // [512]
    int*    flag   = (int*)(ws + (5u << 20));
    float*  gamma_f = smallF;
    float*  gm_f    = smallF + 512;
    float*  gq_f    = smallF + 1024;
    float*  bq_f    = smallF + 1536;
    float*  bo_f    = smallF + 2048;
    float*  b1_f    = smallF + 2560;
    float*  b2_f    = smallF + 3584;

    detect_dtype<<<1, 256, 0, stream>>>(x, flag);
    // transposed (optionally ln-gain-folded) bf16 weights
    transpose_conv<<<2048, 256, 0, stream>>>(W_kv, ln_kv_g, Wt_kv, 512, 1024, flag);
    transpose_conv<<<1024, 256, 0, stream>>>(W_o, nullptr, Wt_o, 512, 512, flag);
    transpose_conv<<<1024, 256, 0, stream>>>(W_emb, ln_m_g, Wt_emb, 512, 512, flag);
    transpose_conv<<<2048, 256, 0, stream>>>(W1, nullptr, Wt_1, 512, 1024, flag);
    transpose_conv<<<2048, 256, 0, stream>>>(W2, nullptr, Wt_2, 1024, 512, flag);
    conv_all<<<16, 256, 0, stream>>>(gamma, gm_mlp, ln_q_g, ln_q_b, b_o, b1, b2,
                                     smallF, flag);
    fold_bias<<<4, 256, 0, stream>>>(W_kv, ln_kv_b, b_kv, bkv_f, 512, 1024, flag);
    fold_bias<<<2, 256, 0, stream>>>(W_emb, ln_m_b, b_emb, bemb_f, 512, 512, flag);

    bool big = ws_size >= ((size_t)480 << 20);
    bf16_t* xh  = (bf16_t*)(ws + ((size_t)8 << 20));    // [65536,512] 64 MiB
    bf16_t* xh2 = (bf16_t*)(ws + ((size_t)72 << 20));   // [65536,512] 64 MiB

    // LN-normalize x -> xh (bf16)
    ln_norm<<<NTOKENS / 4, 256, 0, stream>>>(x, xh, flag);

    if (big) {
        bf16_t* kvC   = (bf16_t*)(ws + ((size_t)136 << 20));  // [65536,1024] 128 MiB
        bf16_t* attnC = (bf16_t*)(ws + ((size_t)264 << 20));  // [65536,512]   64 MiB
        bf16_t* h1C   = kvC;                                  // reuse
        bf16_t* h2C   = (bf16_t*)(ws + ((size_t)328 << 20));  // [65536,1024] 128 MiB

        gemm_bt<0><<<dim3(8, 512), 256, 0, stream>>>(
            xh, Wt_kv, bkv_f, nullptr, nullptr, kvC, flag, 0, 0, 1024, 512);
        attn_win<<<8192, 256, 0, stream>>>(xh, gq_f, bq_f, kvC, attnC, -1);
        gemm_bt<2><<<dim3(4, 512), 256, 0, stream>>>(
            attnC, Wt_o, bo_f, x, gamma_f, d_out, flag, 0, 0, 512, 512);
        ln_norm<<<NTOKENS / 4, 256, 0, stream>>>(d_out, xh2, flag);
        gemm_bt<0><<<dim3(4, 512), 256, 0, stream>>>(
            xh2, Wt_emb, bemb_f, nullptr, nullptr, h1C, flag, 0, 0, 512, 512);
        gemm_bt<1><<<dim3(8, 512), 256, 0, stream>>>(
            h1C, Wt_1, b1_f, nullptr, nullptr, h2C, flag, 0, 0, 1024, 512);
        gemm_bt<2><<<dim3(4, 512), 256, 0, stream>>>(
            h2C, Wt_2, b2_f, d_out, gm_f, d_out, flag, 0, 0, 512, 1024);
        return;
    }

    // ---- fallback: per-plane chunked path (needs ~160 MiB) ----
    bf16_t* kvC16 = (bf16_t*)(ws + ((size_t)136 << 20));  // [8192,1024] 16 MiB
    bf16_t* h1C8  = (bf16_t*)(ws + ((size_t)136 << 20));  // reuse (MLP phase)
    bf16_t* h2C16 = (bf16_t*)(ws + ((size_t)144 << 20));  // [8192,1024] 16 MiB
    bf16_t* attnC8= (bf16_t*)(ws + ((size_t)152 << 20));  // [8192,512]   8 MiB

    for (int p = 0; p < PLANES; p++) {
        int row0 = p * PTOK;
        gemm_bt<0><<<dim3(8, 64), 256, 0, stream>>>(
            xh, Wt_kv, bkv_f, nullptr, nullptr, kvC16, flag, row0, 0, 1024, 512);
        attn_win<<<1024, 256, 0, stream>>>(xh, gq_f, bq_f, kvC16, attnC8, p);
        gemm_bt<2><<<dim3(4, 64), 256, 0, stream>>>(
            attnC8, Wt_o, bo_f, x, gamma_f, d_out, flag, 0, row0, 512, 512);
    }
    ln_norm<<<NTOKENS / 4, 256, 0, stream>>>(d_out, xh2, flag);
    for (int p = 0; p < PLANES; p++) {
        int row0 = p * PTOK;
        gemm_bt<0><<<dim3(4, 64), 256, 0, stream>>>(
            xh2, Wt_emb, bemb_f, nullptr, nullptr, h1C8, flag, row0, 0, 512, 512);
        gemm_bt<1><<<dim3(8, 64), 256, 0, stream>>>(
            h1C8, Wt_1, b1_f, nullptr, nullptr, h2C16, flag, 0, 0, 1024, 512);
        gemm_bt<2><<<dim3(4, 64), 256, 0, stream>>>(
            h2C16, Wt_2, b2_f, d_out, gm_f, d_out, flag, 0, row0, 512, 1024);
    }
}

// Round 3
// 1351.310 us; speedup vs baseline: 1.0166x; 1.0166x over previous
//
#include <hip/hip_runtime.h>

typedef __bf16 bf16_t;
typedef __bf16 bf16x8 __attribute__((ext_vector_type(8)));
typedef float f32x4 __attribute__((ext_vector_type(4)));
typedef float f32x8 __attribute__((ext_vector_type(8)));

#define NTOKENS 65536   // B*V*T*NTOK = 1*2*4*8192
#define PLANES 8        // b*v*t planes, 8192 tokens each
#define PTOK 8192
#define SWIN 128        // windows per plane

static __device__ __forceinline__ f32x4 mfma16(bf16x8 a, bf16x8 b, f32x4 c) {
    return __builtin_amdgcn_mfma_f32_16x16x32_bf16(a, b, c, 0, 0, 0);
}

// async global->LDS, 16B per lane; lds dest must be wave-uniform base
static __device__ __forceinline__ void gld16(const void* g, void* l) {
    __builtin_amdgcn_global_load_lds(
        (const __attribute__((address_space(1))) void*)g,
        (__attribute__((address_space(3))) void*)l, 16, 0, 0);
}

// bijective XCD-chunk swizzle (nwg must be divisible by 8)
static __device__ __forceinline__ int xcd_swz(int lin, int nwg) {
    return (lin & 7) * (nwg >> 3) + (lin >> 3);
}

// ---- dtype-generic accessors (F32: buffer is float, else bf16) ----
template <bool F32>
static __device__ __forceinline__ f32x8 load8f(const void* p, size_t i) {
    f32x8 r;
    if (F32) {
        const f32x4* q = (const f32x4*)((const float*)p + i);
        f32x4 a = q[0], b = q[1];
#pragma unroll
        for (int j = 0; j < 4; j++) { r[j] = a[j]; r[4 + j] = b[j]; }
    } else {
        bf16x8 v = *(const bf16x8*)((const bf16_t*)p + i);
#pragma unroll
        for (int j = 0; j < 8; j++) r[j] = (float)v[j];
    }
    return r;
}
template <bool F32>
static __device__ __forceinline__ float ld1f(const void* p, size_t i) {
    return F32 ? ((const float*)p)[i] : (float)((const bf16_t*)p)[i];
}
template <bool F32>
static __device__ __forceinline__ void st1f(void* p, size_t i, float v) {
    if (F32) ((float*)p)[i] = v; else ((bf16_t*)p)[i] = (bf16_t)v;
}
static __device__ __forceinline__ bf16x8 cvt8(f32x8 f) {
    bf16x8 w;
#pragma unroll
    for (int j = 0; j < 8; j++) w[j] = (bf16_t)f[j];
    return w;
}

// ---- dtype detector: sample even-indexed uint16s of x ----
__global__ void detect_dtype(const void* x, int* flag) {
    __shared__ int cnt[256];
    int t = threadIdx.x;
    const unsigned short* u = (const unsigned short*)x;
    int c = 0;
    for (int i = t; i < 4096; i += 256) {
        int e = (u[2 * i] >> 7) & 0xFF;
        c += (e >= 64 && e <= 140) ? 1 : 0;
    }
    cnt[t] = c;
    __syncthreads();
    for (int s = 128; s > 0; s >>= 1) {
        if (t < s) cnt[t] += cnt[t + s];
        __syncthreads();
    }
    if (t == 0) flag[0] = (cnt[0] < 3072) ? 1 : 0;
}

// ---- weight transpose+convert (+optional per-k gain): dst[n][k]=g[k]*src[k][n]
__global__ void transpose_conv(const void* src, const void* gain, bf16_t* dst,
                               int K, int N, const int* flag) {
    int idx = blockIdx.x * 256 + threadIdx.x;
    if (idx >= K * N) return;
    int n = idx % N, k = idx / N;
    bool f = *flag;
    float v = f ? ((const float*)src)[(size_t)k * N + n]
                : (float)((const bf16_t*)src)[(size_t)k * N + n];
    if (gain) {
        float g = f ? ((const float*)gain)[k] : (float)((const bf16_t*)gain)[k];
        v *= g;
    }
    dst[(size_t)n * K + k] = (bf16_t)v;
}

// ---- folded bias: out[n] = b[n] + sum_k bln[k]*W[k][n]  (f32 out) ----
__global__ void fold_bias(const void* W, const void* bln, const void* b,
                          float* out, int K, int N, const int* flag) {
    int n = blockIdx.x * 256 + threadIdx.x;
    if (n >= N) return;
    bool f = *flag;
    float s = f ? ((const float*)b)[n] : (float)((const bf16_t*)b)[n];
    for (int k = 0; k < K; k++) {
        float bl = f ? ((const float*)bln)[k] : (float)((const bf16_t*)bln)[k];
        float w  = f ? ((const float*)W)[(size_t)k * N + n]
                     : (float)((const bf16_t*)W)[(size_t)k * N + n];
        s += bl * w;
    }
    out[n] = s;
}

// ---- batch convert small vectors to f32 (one launch) ----
// layout in out: gamma[512] gm[512] gq[512] bq[512] bo[512] b1[1024] b2[512]
__global__ void conv_all(const void* gamma, const void* gm, const void* gq,
                         const void* bq, const void* bo, const void* b1,
                         const void* b2, float* out, const int* flag) {
    int idx = blockIdx.x * 256 + threadIdx.x;  // 0..4095
    bool f = *flag;
    const void* src; int off;
    if      (idx < 512)  { src = gamma; off = idx; }
    else if (idx < 1024) { src = gm;    off = idx - 512; }
    else if (idx < 1536) { src = gq;    off = idx - 1024; }
    else if (idx < 2048) { src = bq;    off = idx - 1536; }
    else if (idx < 2560) { src = bo;    off = idx - 2048; }
    else if (idx < 3584) { src = b1;    off = idx - 2560; }
    else                 { src = b2;    off = idx - 3584; }
    out[idx] = f ? ((const float*)src)[off] : (float)((const bf16_t*)src)[off];
}

// ---- fused LN-normalize: xh[row] = (x[row]-mean)*rstd  (bf16 out) ----
template <bool F32>
static __device__ __forceinline__ void ln_norm_body(const void* x, bf16_t* xh) {
    int wave = threadIdx.x >> 6, lane = threadIdx.x & 63;
    size_t row = (size_t)blockIdx.x * 4 + wave;
    f32x8 f = load8f<F32>(x, row * 512 + lane * 8);
    float s = 0.f, s2 = 0.f;
#pragma unroll
    for (int j = 0; j < 8; j++) { s += f[j]; s2 += f[j] * f[j]; }
#pragma unroll
    for (int off = 32; off > 0; off >>= 1) { s += __shfl_xor(s, off); s2 += __shfl_xor(s2, off); }
    float m = s * (1.f / 512.f);
    float var = s2 * (1.f / 512.f) - m * m;
    float r = 1.f / sqrtf(var + 1e-5f);
    bf16x8 o;
#pragma unroll
    for (int j = 0; j < 8; j++) o[j] = (bf16_t)((f[j] - m) * r);
    *(bf16x8*)(xh + row * 512 + lane * 8) = o;
}
__global__ __launch_bounds__(256) void ln_norm(const void* x, bf16_t* xh,
                                               const int* flag) {
    if (*flag) ln_norm_body<true>(x, xh);
    else       ln_norm_body<false>(x, xh);
}

// ---- pure bf16 GEMM: C = epi(A[M,K] @ Bt[N,K]^T + bias) ----
// EPI 0: +bias   EPI 1: gelu(+bias)   EPI 2: res + gamma*(+bias) (res/C dtype F32)
// 2-phase double-buffered pipeline; LDS tiles slot-XOR-swizzled on BOTH the
// global_load_lds source address and the ds_read address (rule #21).
// LDS layout: tile row r (0..127), 16-B slot s' (0..3): holds global slot
// s = s' ^ ((r>>1)&3).  Read of (r, slot q) -> elem r*32 + (q^((r>>1)&3))*8.
template <int EPI, bool F32>
static __device__ __forceinline__ void gemm_body(
    bf16_t (*LDS)[4096],
    const bf16_t* A, const bf16_t* Bt, const float* bias, const void* res,
    const float* gamma, void* C, int arow0, int rrow0, int N, int K) {
    int t = threadIdx.x;
    int gx = gridDim.x;
    int nwg = gx * gridDim.y;
    int lin = blockIdx.y * gx + blockIdx.x;
    int s = xcd_swz(lin, nwg);
    int m0 = (s / gx) * 128, n0 = (s % gx) * 128;
    int wave = t >> 6, lane = t & 63, q = lane >> 4, li = lane & 15;
    int wm = (wave >> 1) * 64, wn = (wave & 1) * 64;
    const f32x4 fzero = {0.f, 0.f, 0.f, 0.f};
    f32x4 acc[4][4];
#pragma unroll
    for (int i = 0; i < 4; i++)
#pragma unroll
        for (int n = 0; n < 4; n++) acc[i][n] = fzero;

    // staging: wave w, lane ln writes LDS bytes {w*1024 + ln*16} (+4096 for
    // rows 64..127) -> row = [64h+] w*16 + ln/4, slot s' = ln&3. Source must
    // be global slot s'^swz(row).  ((row+64)>>1)&3 == (row>>1)&3 -> one scol.
    int srow = wave * 16 + (lane >> 2);
    int scol = (((lane & 3) ^ ((srow >> 1) & 3)) << 3);
    const bf16_t* gA = A + (size_t)(arow0 + m0 + srow) * K + scol;
    const bf16_t* gB = Bt + (size_t)(n0 + srow) * K + scol;
    const size_t half = (size_t)64 * K;

    // swizzled LDS read offsets (elem units)
    int offA[4], offB[4];
#pragma unroll
    for (int i = 0; i < 4; i++) {
        int Ra = wm + 16 * i + li;
        offA[i] = Ra * 32 + ((q ^ ((Ra >> 1) & 3)) << 3);
        int Rb = wn + 16 * i + li;
        offB[i] = Rb * 32 + ((q ^ ((Rb >> 1) & 3)) << 3);
    }

    auto STAGE = [&](int k0, int c) {
        bf16_t* pa = &LDS[c][wave * 512];
        bf16_t* pb = &LDS[2 + c][wave * 512];
        gld16(gA + k0, pa);
        gld16(gA + half + k0, pa + 2048);
        gld16(gB + k0, pb);
        gld16(gB + half + k0, pb + 2048);
    };
    auto COMPUTE = [&](int c) {
        bf16x8 af[4], bfr[4];
#pragma unroll
        for (int i = 0; i < 4; i++) af[i] = *(const bf16x8*)&LDS[c][offA[i]];
#pragma unroll
        for (int n = 0; n < 4; n++) bfr[n] = *(const bf16x8*)&LDS[2 + c][offB[n]];
#pragma unroll
        for (int i = 0; i < 4; i++)
#pragma unroll
            for (int n = 0; n < 4; n++) acc[i][n] = mfma16(af[i], bfr[n], acc[i][n]);
    };

    STAGE(0, 0);
    __syncthreads();
    int nt = K >> 5;   // 16 or 32, always even
    for (int tt = 0; tt < nt; tt += 2) {
        STAGE((tt + 1) << 5, 1);
        COMPUTE(0);
        __syncthreads();
        if (tt + 2 < nt) STAGE((tt + 2) << 5, 0);
        COMPUTE(1);
        __syncthreads();
    }

    if (EPI <= 1) {
        // coalesced epilogue: wave-private 64x64 bf16 chunk in LDS, slot-XOR
        // swizzled (slot' = slot ^ (row&7)) so scalar writes are ~2-way and
        // vector reads are conflict-free; stores become 128-B full lines.
        bf16_t* ch = &LDS[wave][0];
#pragma unroll
        for (int n = 0; n < 4; n++) {
            float bv = bias[n0 + wn + 16 * n + li];
#pragma unroll
            for (int i = 0; i < 4; i++) {
#pragma unroll
                for (int r = 0; r < 4; r++) {
                    float v = acc[i][n][r] + bv;
                    if (EPI == 1) {
                        float u = v;
                        v = 0.5f * u * (1.f + tanhf(0.7978845608028654f * (u + 0.044715f * u * u * u)));
                    }
                    int row = 16 * i + q * 4 + r;
                    int sl = (((2 * n + (li >> 3)) ^ (row & 7)) << 3) + (li & 7);
                    ch[row * 64 + sl] = (bf16_t)v;
                }
            }
        }
        asm volatile("s_waitcnt lgkmcnt(0)" ::: "memory");
        __builtin_amdgcn_sched_barrier(0);
#pragma unroll
        for (int p = 0; p < 8; p++) {
            int rl = p * 8 + (lane >> 3);
            int sl = (((lane & 7) ^ (rl & 7)) << 3);
            bf16x8 v8 = *(const bf16x8*)&ch[rl * 64 + sl];
            *(bf16x8*)((bf16_t*)C + (size_t)(m0 + wm + rl) * N + n0 + wn +
                       ((lane & 7) << 3)) = v8;
        }
    } else {
        // EPI 2: residual epilogue (possibly f32 I/O), scattered
#pragma unroll
        for (int n = 0; n < 4; n++) {
            int col = n0 + wn + 16 * n + li;
            float bv = bias[col];
            float gv = gamma[col];
#pragma unroll
            for (int i = 0; i < 4; i++) {
                int rowb = m0 + wm + 16 * i + q * 4;
#pragma unroll
                for (int r = 0; r < 4; r++) {
                    float v = acc[i][n][r] + bv;
                    size_t idx = (size_t)(rrow0 + rowb + r) * N + col;
                    v = ld1f<F32>(res, idx) + gv * v;
                    st1f<F32>(C, idx, v);
                }
            }
        }
    }
}
template <int EPI>
__global__ __launch_bounds__(256) void gemm_bt(
    const bf16_t* A, const bf16_t* Bt, const float* bias, const void* res,
    const float* gamma, void* C, const int* flag,
    int arow0, int rrow0, int N, int K) {
    __shared__ __align__(16) bf16_t LDS[4][4096];   // 32 KiB: A0,A1,B0,B1
    if constexpr (EPI == 2) {
        if (*flag) {
            gemm_body<EPI, true>(LDS, A, Bt, bias, res, gamma, C, arow0, rrow0, N, K);
            return;
        }
    }
    gemm_body<EPI, false>(LDS, A, Bt, bias, res, gamma, C, arow0, rrow0, N, K);
}

// ---- windowed attention (reads pre-normalized bf16 xh; gq/bq f32) ----
// plane >= 0: per-plane mode, grid = 1024, kv/outc plane-local.
// plane < 0 : full-batch mode, grid = 8192, plane from blockIdx, kv/outc global.
__global__ __launch_bounds__(256) void attn_win(
    const bf16_t* xh, const float* gq, const float* bq,
    const bf16_t* kv, bf16_t* outc, int plane) {
    __shared__ __align__(16) char smem[62464];
    bf16_t(*Ql)[72] = (bf16_t(*)[72])smem;            // 64x72  (9216 B)
    bf16_t(*Kl)[72] = (bf16_t(*)[72])(smem + 9216);   // 192x72 (27648 B)
    bf16_t(*Pl)[200] = (bf16_t(*)[200])smem;          // 64x200 overlaps Ql/Kl (dead)
    bf16_t(*Vt)[200] = (bf16_t(*)[200])(smem + 36864);// 64x200, Vt[d][key]

    int blk = xcd_swz(blockIdx.x, gridDim.x);
    bool full = (plane < 0);
    if (full) { plane = blk >> 10; blk &= 1023; }
    int wl = blk >> 3, h = blk & 7;     // window-in-plane, head
    int i = wl;
    int t = threadIdx.x, wave = t >> 6, lane = t & 63, q = lane >> 4, li = lane & 15;
    size_t qg = (size_t)plane * PTOK + (size_t)wl * 64;   // global token base
    size_t ob = full ? qg : (size_t)wl * 64;              // output token base
    const bf16_t* kvp = full ? kv + (size_t)plane * PTOK * 1024 : kv;

    // stage Q (64x64): xh * g_q + b_q
#pragma unroll
    for (int l = t; l < 512; l += 256) {
        int row = l >> 3, seg = l & 7;
        f32x8 xv = load8f<false>(xh, (qg + row) * 512 + h * 64 + seg * 8);
        f32x8 gv = load8f<true>(gq, h * 64 + seg * 8);
        f32x8 bv = load8f<true>(bq, h * 64 + seg * 8);
        f32x8 w;
#pragma unroll
        for (int j = 0; j < 8; j++) w[j] = xv[j] * gv[j] + bv[j];
        *(bf16x8*)&Ql[row][seg * 8] = cvt8(w);
    }
    // stage K (192x64) and V transposed (Vt[d][key]); kvp is plane-local
#pragma unroll
    for (int l = t; l < 1536; l += 256) {
        int row = l >> 3, seg = l & 7;
        int nb = i + (row >> 6) - 1;
        nb = nb < 0 ? 0 : (nb > SWIN - 1 ? SWIN - 1 : nb);
        size_t tok = (size_t)nb * 64 + (row & 63);
        *(bf16x8*)&Kl[row][seg * 8] =
            *(const bf16x8*)&kvp[tok * 1024 + h * 64 + seg * 8];
        bf16x8 vv = *(const bf16x8*)&kvp[tok * 1024 + 512 + h * 64 + seg * 8];
#pragma unroll
        for (int j = 0; j < 8; j++) Vt[seg * 8 + j][row] = vv[j];
    }
    __syncthreads();

    int rm = wave * 16;
    const f32x4 fzero = {0.f, 0.f, 0.f, 0.f};
    f32x4 sc[12];
#pragma unroll
    for (int nt = 0; nt < 12; nt++) sc[nt] = fzero;
#pragma unroll
    for (int ks = 0; ks < 2; ks++) {
        bf16x8 aq = *(const bf16x8*)&Ql[rm + li][ks * 32 + q * 8];
#pragma unroll
        for (int nt = 0; nt < 12; nt++) {
            bf16x8 bk = *(const bf16x8*)&Kl[16 * nt + li][ks * 32 + q * 8];
            sc[nt] = mfma16(aq, bk, sc[nt]);
        }
    }
    // mask + softmax (row q*4+r, key = 16*nt+li)
    bool v0 = (i > 0), v2 = (i < SWIN - 1);
    float mx[4] = {-3e38f, -3e38f, -3e38f, -3e38f};
#pragma unroll
    for (int nt = 0; nt < 12; nt++) {
        bool valid = (nt < 4) ? v0 : ((nt >= 8) ? v2 : true);
#pragma unroll
        for (int r = 0; r < 4; r++) {
            float sv = valid ? sc[nt][r] * 0.125f : -3e38f;
            sc[nt][r] = sv;
            mx[r] = fmaxf(mx[r], sv);
        }
    }
#pragma unroll
    for (int r = 0; r < 4; r++)
#pragma unroll
        for (int msk = 1; msk < 16; msk <<= 1)
            mx[r] = fmaxf(mx[r], __shfl_xor(mx[r], msk));
    float lsum[4] = {0.f, 0.f, 0.f, 0.f};
#pragma unroll
    for (int nt = 0; nt < 12; nt++)
#pragma unroll
        for (int r = 0; r < 4; r++) {
            float e = __expf(sc[nt][r] - mx[r]);
            sc[nt][r] = e;
            lsum[r] += e;
        }
#pragma unroll
    for (int r = 0; r < 4; r++)
#pragma unroll
        for (int msk = 1; msk < 16; msk <<= 1)
            lsum[r] += __shfl_xor(lsum[r], msk);

    __syncthreads();  // all waves done with Ql/Kl before Pl overwrites
#pragma unroll
    for (int nt = 0; nt < 12; nt++)
#pragma unroll
        for (int r = 0; r < 4; r++)
            Pl[rm + q * 4 + r][16 * nt + li] = (bf16_t)sc[nt][r];
    __syncthreads();

    f32x4 o[4];
#pragma unroll
    for (int nt = 0; nt < 4; nt++) o[nt] = fzero;
#pragma unroll
    for (int ks = 0; ks < 6; ks++) {
        bf16x8 ap = *(const bf16x8*)&Pl[rm + li][ks * 32 + q * 8];
#pragma unroll
        for (int nt = 0; nt < 4; nt++) {
            bf16x8 bv = *(const bf16x8*)&Vt[16 * nt + li][ks * 32 + q * 8];
            o[nt] = mfma16(ap, bv, o[nt]);
        }
    }
#pragma unroll
    for (int r = 0; r < 4; r++) {
        float inv = 1.f / lsum[r];
        size_t tokr = ob + rm + q * 4 + r;
#pragma unroll
        for (int nt = 0; nt < 4; nt++)
            outc[tokr * 512 + h * 64 + 16 * nt + li] = (bf16_t)(o[nt][r] * inv);
    }
}

extern "C" void kernel_launch(void* const* d_in, const int* in_sizes, int n_in,
                              void* d_out, int out_size, void* d_ws, size_t ws_size,
                              hipStream_t stream) {
    const void* x      = d_in[0];
    const void* ln_q_g = d_in[1];
    const void* ln_q_b = d_in[2];
    const void* ln_kv_g= d_in[3];
    const void* ln_kv_b= d_in[4];
    const void* W_kv   = d_in[5];
    const void* b_kv   = d_in[6];
    const void* W_o    = d_in[7];
    const void* b_o    = d_in[8];
    const void* gamma  = d_in[9];
    const void* ln_m_g = d_in[10];
    const void* ln_m_b = d_in[11];
    const void* W_emb  = d_in[12];
    const void* b_emb  = d_in[13];
    const void* W1     = d_in[14];
    const void* b1     = d_in[15];
    const void* W2     = d_in[16];
    const void* b2     = d_in[17];
    const void* gm_mlp = d_in[18];
    char* ws = (char*)d_ws;

    // fixed small region
    bf16_t* Wt_kv  = (bf16_t*)(ws);                     // [1024,512]  1 MiB
    bf16_t* Wt_o   = (bf16_t*)(ws + (1u << 20));        // [512,512]
    bf16_t* Wt_emb = (bf16_t*)(ws + 1572864);           // [512,512]
    bf16_t* Wt_1   = (bf16_t*)(ws + (2u << 20));        // [1024,512]
    bf16_t* Wt_2   = (bf16_t*)(ws + (3u << 20));        // [512,1024]
    float*  smallF = (float*)(ws + (4u << 20));         // 16 KiB f32 consts
    float*  bkv_f  = (float*)(ws + (4u << 20) + 16384); // [1024]
    float*  bemb_f = (float*)(ws + (4u << 20) + 20480); // [512]
    int*    flag   = (int*)(ws + (5u << 20));
    float*  gamma_f = smallF;
    float*  gm_f    = smallF + 512;
    float*  gq_f    = smallF + 1024;
    float*  bq_f    = smallF + 1536;
    float*  bo_f    = smallF + 2048;
    float*  b1_f    = smallF + 2560;
    float*  b2_f    = smallF + 3584;

    detect_dtype<<<1, 256, 0, stream>>>(x, flag);
    // transposed (optionally ln-gain-folded) bf16 weights
    transpose_conv<<<2048, 256, 0, stream>>>(W_kv, ln_kv_g, Wt_kv, 512, 1024, flag);
    transpose_conv<<<1024, 256, 0, stream>>>(W_o, nullptr, Wt_o, 512, 512, flag);
    transpose_conv<<<1024, 256, 0, stream>>>(W_emb, ln_m_g, Wt_emb, 512, 512, flag);
    transpose_conv<<<2048, 256, 0, stream>>>(W1, nullptr, Wt_1, 512, 1024, flag);
    transpose_conv<<<2048, 256, 0, stream>>>(W2, nullptr, Wt_2, 1024, 512, flag);
    conv_all<<<16, 256, 0, stream>>>(gamma, gm_mlp, ln_q_g, ln_q_b, b_o, b1, b2,
                                     smallF, flag);
    fold_bias<<<4, 256, 0, stream>>>(W_kv, ln_kv_b, b_kv, bkv_f, 512, 1024, flag);
    fold_bias<<<2, 256, 0, stream>>>(W_emb, ln_m_b, b_emb, bemb_f, 512, 512, flag);

    bool big = ws_size >= ((size_t)480 << 20);
    bf16_t* xh  = (bf16_t*)(ws + ((size_t)8 << 20));    // [65536,512] 64 MiB
    bf16_t* xh2 = (bf16_t*)(ws + ((size_t)72 << 20));   // [65536,512] 64 MiB

    // LN-normalize x -> xh (bf16)
    ln_norm<<<NTOKENS / 4, 256, 0, stream>>>(x, xh, flag);

    if (big) {
        bf16_t* kvC   = (bf16_t*)(ws + ((size_t)136 << 20));  // [65536,1024] 128 MiB
        bf16_t* attnC = (bf16_t*)(ws + ((size_t)264 << 20));  // [65536,512]   64 MiB
        bf16_t* h1C   = kvC;                                  // reuse
        bf16_t* h2C   = (bf16_t*)(ws + ((size_t)328 << 20));  // [65536,1024] 128 MiB

        gemm_bt<0><<<dim3(8, 512), 256, 0, stream>>>(
            xh, Wt_kv, bkv_f, nullptr, nullptr, kvC, flag, 0, 0, 1024, 512);
        attn_win<<<8192, 256, 0, stream>>>(xh, gq_f, bq_f, kvC, attnC, -1);
        gemm_bt<2><<<dim3(4, 512), 256, 0, stream>>>(
            attnC, Wt_o, bo_f, x, gamma_f, d_out, flag, 0, 0, 512, 512);
        ln_norm<<<NTOKENS / 4, 256, 0, stream>>>(d_out, xh2, flag);
        gemm_bt<0><<<dim3(4, 512), 256, 0, stream>>>(
            xh2, Wt_emb, bemb_f, nullptr, nullptr, h1C, flag, 0, 0, 512, 512);
        gemm_bt<1><<<dim3(8, 512), 256, 0, stream>>>(
            h1C, Wt_1, b1_f, nullptr, nullptr, h2C, flag, 0, 0, 1024, 512);
        gemm_bt<2><<<dim3(4, 512), 256, 0, stream>>>(
            h2C, Wt_2, b2_f, d_out, gm_f, d_out, flag, 0, 0, 512, 1024);
        return;
    }

    // ---- fallback: per-plane chunked path (needs ~160 MiB) ----
    bf16_t* kvC16 = (bf16_t*)(ws + ((size_t)136 << 20));  // [8192,1024] 16 MiB
    bf16_t* h1C8  = (bf16_t*)(ws + ((size_t)136 << 20));  // reuse (MLP phase)
    bf16_t* h2C16 = (bf16_t*)(ws + ((size_t)144 << 20));  // [8192,1024] 16 MiB
    bf16_t* attnC8= (bf16_t*)(ws + ((size_t)152 << 20));  // [8192,512]   8 MiB

    for (int p = 0; p < PLANES; p++) {
        int row0 = p * PTOK;
        gemm_bt<0><<<dim3(8, 64), 256, 0, stream>>>(
            xh, Wt_kv, bkv_f, nullptr, nullptr, kvC16, flag, row0, 0, 1024, 512);
        attn_win<<<1024, 256, 0, stream>>>(xh, gq_f, bq_f, kvC16, attnC8, p);
        gemm_bt<2><<<dim3(4, 64), 256, 0, stream>>>(
            attnC8, Wt_o, bo_f, x, gamma_f, d_out, flag, 0, row0, 512, 512);
    }
    ln_norm<<<NTOKENS / 4, 256, 0, stream>>>(d_out, xh2, flag);
    for (int p = 0; p < PLANES; p++) {
        int row0 = p * PTOK;
        gemm_bt<0><<<dim3(4, 64), 256, 0, stream>>>(
            xh2, Wt_emb, bemb_f, nullptr, nullptr, h1C8, flag, row0, 0, 512, 512);
        gemm_bt<1><<<dim3(8, 64), 256, 0, stream>>>(
            h1C8, Wt_1, b1_f, nullptr, nullptr, h2C16, flag, 0, 0, 1024, 512);
        gemm_bt<2><<<dim3(4, 64), 256, 0, stream>>>(
            h2C16, Wt_2, b2_f, d_out, gm_f, d_out, flag, 0, row0, 512, 1024);
    }
}

// Round 4
// 1134.475 us; speedup vs baseline: 1.2109x; 1.1911x over previous
//
#include <hip/hip_runtime.h>

typedef __bf16 bf16_t;
typedef __bf16 bf16x8 __attribute__((ext_vector_type(8)));
typedef float f32x4 __attribute__((ext_vector_type(4)));
typedef float f32x8 __attribute__((ext_vector_type(8)));

#define NTOKENS 65536   // B*V*T*NTOK = 1*2*4*8192
#define PLANES 8        // b*v*t planes, 8192 tokens each
#define PTOK 8192
#define SWIN 128        // windows per plane

static __device__ __forceinline__ f32x4 mfma16(bf16x8 a, bf16x8 b, f32x4 c) {
    return __builtin_amdgcn_mfma_f32_16x16x32_bf16(a, b, c, 0, 0, 0);
}

// async global->LDS, 16B per lane; lds dest must be wave-uniform base
static __device__ __forceinline__ void gld16(const void* g, void* l) {
    __builtin_amdgcn_global_load_lds(
        (const __attribute__((address_space(1))) void*)g,
        (__attribute__((address_space(3))) void*)l, 16, 0, 0);
}

// bijective XCD-chunk swizzle (nwg must be divisible by 8)
static __device__ __forceinline__ int xcd_swz(int lin, int nwg) {
    return (lin & 7) * (nwg >> 3) + (lin >> 3);
}

// ---- dtype-generic accessors (F32: buffer is float, else bf16) ----
template <bool F32>
static __device__ __forceinline__ f32x8 load8f(const void* p, size_t i) {
    f32x8 r;
    if (F32) {
        const f32x4* q = (const f32x4*)((const float*)p + i);
        f32x4 a = q[0], b = q[1];
#pragma unroll
        for (int j = 0; j < 4; j++) { r[j] = a[j]; r[4 + j] = b[j]; }
    } else {
        bf16x8 v = *(const bf16x8*)((const bf16_t*)p + i);
#pragma unroll
        for (int j = 0; j < 8; j++) r[j] = (float)v[j];
    }
    return r;
}
template <bool F32>
static __device__ __forceinline__ float ld1f(const void* p, size_t i) {
    return F32 ? ((const float*)p)[i] : (float)((const bf16_t*)p)[i];
}
template <bool F32>
static __device__ __forceinline__ void st1f(void* p, size_t i, float v) {
    if (F32) ((float*)p)[i] = v; else ((bf16_t*)p)[i] = (bf16_t)v;
}
static __device__ __forceinline__ bf16x8 cvt8(f32x8 f) {
    bf16x8 w;
#pragma unroll
    for (int j = 0; j < 8; j++) w[j] = (bf16_t)f[j];
    return w;
}

// ---- dtype detector: sample even-indexed uint16s of x ----
__global__ void detect_dtype(const void* x, int* flag) {
    __shared__ int cnt[256];
    int t = threadIdx.x;
    const unsigned short* u = (const unsigned short*)x;
    int c = 0;
    for (int i = t; i < 4096; i += 256) {
        int e = (u[2 * i] >> 7) & 0xFF;
        c += (e >= 64 && e <= 140) ? 1 : 0;
    }
    cnt[t] = c;
    __syncthreads();
    for (int s = 128; s > 0; s >>= 1) {
        if (t < s) cnt[t] += cnt[t + s];
        __syncthreads();
    }
    if (t == 0) flag[0] = (cnt[0] < 3072) ? 1 : 0;
}

// ---- weight transpose+convert (+optional per-k gain): dst[n][k]=g[k]*src[k][n]
__global__ void transpose_conv(const void* src, const void* gain, bf16_t* dst,
                               int K, int N, const int* flag) {
    int idx = blockIdx.x * 256 + threadIdx.x;
    if (idx >= K * N) return;
    int n = idx % N, k = idx / N;
    bool f = *flag;
    float v = f ? ((const float*)src)[(size_t)k * N + n]
                : (float)((const bf16_t*)src)[(size_t)k * N + n];
    if (gain) {
        float g = f ? ((const float*)gain)[k] : (float)((const bf16_t*)gain)[k];
        v *= g;
    }
    dst[(size_t)n * K + k] = (bf16_t)v;
}

// ---- folded bias: out[n] = b[n] + sum_k bln[k]*W[k][n]  (f32 out) ----
__global__ void fold_bias(const void* W, const void* bln, const void* b,
                          float* out, int K, int N, const int* flag) {
    int n = blockIdx.x * 256 + threadIdx.x;
    if (n >= N) return;
    bool f = *flag;
    float s = f ? ((const float*)b)[n] : (float)((const bf16_t*)b)[n];
    for (int k = 0; k < K; k++) {
        float bl = f ? ((const float*)bln)[k] : (float)((const bf16_t*)bln)[k];
        float w  = f ? ((const float*)W)[(size_t)k * N + n]
                     : (float)((const bf16_t*)W)[(size_t)k * N + n];
        s += bl * w;
    }
    out[n] = s;
}

// ---- batch convert small vectors to f32 (one launch) ----
// layout in out: gamma[512] gm[512] gq[512] bq[512] bo[512] b1[1024] b2[512]
__global__ void conv_all(const void* gamma, const void* gm, const void* gq,
                         const void* bq, const void* bo, const void* b1,
                         const void* b2, float* out, const int* flag) {
    int idx = blockIdx.x * 256 + threadIdx.x;  // 0..4095
    bool f = *flag;
    const void* src; int off;
    if      (idx < 512)  { src = gamma; off = idx; }
    else if (idx < 1024) { src = gm;    off = idx - 512; }
    else if (idx < 1536) { src = gq;    off = idx - 1024; }
    else if (idx < 2048) { src = bq;    off = idx - 1536; }
    else if (idx < 2560) { src = bo;    off = idx - 2048; }
    else if (idx < 3584) { src = b1;    off = idx - 2560; }
    else                 { src = b2;    off = idx - 3584; }
    out[idx] = f ? ((const float*)src)[off] : (float)((const bf16_t*)src)[off];
}

// ---- fused LN-normalize: xh[row] = (x[row]-mean)*rstd  (bf16 out) ----
template <bool F32>
static __device__ __forceinline__ void ln_norm_body(const void* x, bf16_t* xh) {
    int wave = threadIdx.x >> 6, lane = threadIdx.x & 63;
    size_t row = (size_t)blockIdx.x * 4 + wave;
    f32x8 f = load8f<F32>(x, row * 512 + lane * 8);
    float s = 0.f, s2 = 0.f;
#pragma unroll
    for (int j = 0; j < 8; j++) { s += f[j]; s2 += f[j] * f[j]; }
#pragma unroll
    for (int off = 32; off > 0; off >>= 1) { s += __shfl_xor(s, off); s2 += __shfl_xor(s2, off); }
    float m = s * (1.f / 512.f);
    float var = s2 * (1.f / 512.f) - m * m;
    float r = 1.f / sqrtf(var + 1e-5f);
    bf16x8 o;
#pragma unroll
    for (int j = 0; j < 8; j++) o[j] = (bf16_t)((f[j] - m) * r);
    *(bf16x8*)(xh + row * 512 + lane * 8) = o;
}
__global__ __launch_bounds__(256) void ln_norm(const void* x, bf16_t* xh,
                                               const int* flag) {
    if (*flag) ln_norm_body<true>(x, xh);
    else       ln_norm_body<false>(x, xh);
}

// ---- pure bf16 GEMM: C = epi(A[M,K] @ Bt[N,K]^T + bias) ----
// EPI 0: +bias   EPI 1: gelu(+bias)   EPI 2: res + gamma*(+bias) (res/C dtype F32)
// 3-deep prefetch pipeline with counted vmcnt across raw barriers (T4):
// prologue stages tiles 0,1,2; steady phase waits vmcnt(8) (2 tiles stay in
// flight across both barriers), computes tile t, then after the read-release
// barrier stages tile t+3 into the buffer just consumed. Drain to 0 only at
// the tail. LDS tiles slot-XOR-swizzled on BOTH the global_load_lds source
// address and the ds_read address (rule #21):
// tile row r (0..127), 16-B slot s' (0..3) holds global slot s = s'^((r>>1)&3).
template <int EPI, bool F32>
static __device__ __forceinline__ void gemm_body(
    bf16_t (*LDS)[4096],
    const bf16_t* A, const bf16_t* Bt, const float* bias, const void* res,
    const float* gamma, void* C, int arow0, int rrow0, int N, int K) {
    int t = threadIdx.x;
    int gx = gridDim.x;
    int nwg = gx * gridDim.y;
    int lin = blockIdx.y * gx + blockIdx.x;
    int s = xcd_swz(lin, nwg);
    int m0 = (s / gx) * 128, n0 = (s % gx) * 128;
    int wave = t >> 6, lane = t & 63, q = lane >> 4, li = lane & 15;
    int wm = (wave >> 1) * 64, wn = (wave & 1) * 64;
    const f32x4 fzero = {0.f, 0.f, 0.f, 0.f};
    f32x4 acc[4][4];
#pragma unroll
    for (int i = 0; i < 4; i++)
#pragma unroll
        for (int n = 0; n < 4; n++) acc[i][n] = fzero;

    // staging: wave w, lane ln writes LDS bytes {w*1024 + ln*16} (+4096 for
    // rows 64..127) -> row = [64h+] w*16 + ln/4, slot s' = ln&3. Source must
    // be global slot s'^swz(row).  ((row+64)>>1)&3 == (row>>1)&3 -> one scol.
    int srow = wave * 16 + (lane >> 2);
    int scol = (((lane & 3) ^ ((srow >> 1) & 3)) << 3);
    const bf16_t* gA = A + (size_t)(arow0 + m0 + srow) * K + scol;
    const bf16_t* gB = Bt + (size_t)(n0 + srow) * K + scol;
    const size_t half = (size_t)64 * K;

    // swizzled LDS read offsets (elem units)
    int offA[4], offB[4];
#pragma unroll
    for (int i = 0; i < 4; i++) {
        int Ra = wm + 16 * i + li;
        offA[i] = Ra * 32 + ((q ^ ((Ra >> 1) & 3)) << 3);
        int Rb = wn + 16 * i + li;
        offB[i] = Rb * 32 + ((q ^ ((Rb >> 1) & 3)) << 3);
    }

    auto STAGE = [&](int k0, int c) {
        bf16_t* pa = &LDS[c][wave * 512];
        bf16_t* pb = &LDS[3 + c][wave * 512];
        gld16(gA + k0, pa);
        gld16(gA + half + k0, pa + 2048);
        gld16(gB + k0, pb);
        gld16(gB + half + k0, pb + 2048);
    };
    auto COMPUTE = [&](int c) {
        bf16x8 af[4], bfr[4];
#pragma unroll
        for (int i = 0; i < 4; i++) af[i] = *(const bf16x8*)&LDS[c][offA[i]];
#pragma unroll
        for (int n = 0; n < 4; n++) bfr[n] = *(const bf16x8*)&LDS[3 + c][offB[n]];
#pragma unroll
        for (int i = 0; i < 4; i++)
#pragma unroll
            for (int n = 0; n < 4; n++) acc[i][n] = mfma16(af[i], bfr[n], acc[i][n]);
    };

    int nt = K >> 5;   // 16 or 32
    STAGE(0, 0);
    STAGE(32, 1);
    STAGE(64, 2);
    int c = 0;
    for (int tt = 0; tt < nt; tt++) {
        if (tt + 2 < nt)      asm volatile("s_waitcnt vmcnt(8)" ::: "memory");
        else if (tt + 1 < nt) asm volatile("s_waitcnt vmcnt(4)" ::: "memory");
        else                  asm volatile("s_waitcnt vmcnt(0)" ::: "memory");
        __builtin_amdgcn_s_barrier();
        __builtin_amdgcn_sched_barrier(0);
        COMPUTE(c);
        __builtin_amdgcn_sched_barrier(0);
        asm volatile("s_waitcnt lgkmcnt(0)" ::: "memory");
        __builtin_amdgcn_s_barrier();
        __builtin_amdgcn_sched_barrier(0);
        if (tt + 3 < nt) STAGE((tt + 3) << 5, c);
        c = (c == 2) ? 0 : c + 1;
    }

    if (EPI <= 1) {
        // coalesced epilogue: wave-private 64x64 bf16 chunk in LDS, slot-XOR
        // swizzled (slot' = slot ^ (row&7)); stores become 128-B full lines.
        bf16_t* ch = &LDS[wave][0];
#pragma unroll
        for (int n = 0; n < 4; n++) {
            float bv = bias[n0 + wn + 16 * n + li];
#pragma unroll
            for (int i = 0; i < 4; i++) {
#pragma unroll
                for (int r = 0; r < 4; r++) {
                    float v = acc[i][n][r] + bv;
                    if (EPI == 1) {
                        float u = v;
                        v = 0.5f * u * (1.f + tanhf(0.7978845608028654f * (u + 0.044715f * u * u * u)));
                    }
                    int row = 16 * i + q * 4 + r;
                    int sl = (((2 * n + (li >> 3)) ^ (row & 7)) << 3) + (li & 7);
                    ch[row * 64 + sl] = (bf16_t)v;
                }
            }
        }
        asm volatile("s_waitcnt lgkmcnt(0)" ::: "memory");
        __builtin_amdgcn_sched_barrier(0);
#pragma unroll
        for (int p = 0; p < 8; p++) {
            int rl = p * 8 + (lane >> 3);
            int sl = (((lane & 7) ^ (rl & 7)) << 3);
            bf16x8 v8 = *(const bf16x8*)&ch[rl * 64 + sl];
            *(bf16x8*)((bf16_t*)C + (size_t)(m0 + wm + rl) * N + n0 + wn +
                       ((lane & 7) << 3)) = v8;
        }
    } else {
        // EPI 2: residual epilogue, also via LDS chunk for coalesced I/O.
        // chunk holds raw acc (bias/gamma applied at read time, per-column).
        bf16_t* ch = &LDS[wave][0];
#pragma unroll
        for (int n = 0; n < 4; n++) {
#pragma unroll
            for (int i = 0; i < 4; i++) {
#pragma unroll
                for (int r = 0; r < 4; r++) {
                    int row = 16 * i + q * 4 + r;
                    int sl = (((2 * n + (li >> 3)) ^ (row & 7)) << 3) + (li & 7);
                    ch[row * 64 + sl] = (bf16_t)acc[i][n][r];
                }
            }
        }
        asm volatile("s_waitcnt lgkmcnt(0)" ::: "memory");
        __builtin_amdgcn_sched_barrier(0);
        int colb = n0 + wn + ((lane & 7) << 3);
        f32x8 gv8 = load8f<true>(gamma, colb);
        f32x8 bv8 = load8f<true>(bias, colb);
#pragma unroll
        for (int p = 0; p < 8; p++) {
            int rl = p * 8 + (lane >> 3);
            int sl = (((lane & 7) ^ (rl & 7)) << 3);
            bf16x8 v8 = *(const bf16x8*)&ch[rl * 64 + sl];
            size_t base = (size_t)(rrow0 + m0 + wm + rl) * N + colb;
            f32x8 rv = load8f<F32>(res, base);
            f32x8 ov;
#pragma unroll
            for (int j = 0; j < 8; j++)
                ov[j] = rv[j] + gv8[j] * ((float)v8[j] + bv8[j]);
            if (F32) {
                f32x4 o0, o1;
#pragma unroll
                for (int j = 0; j < 4; j++) { o0[j] = ov[j]; o1[j] = ov[4 + j]; }
                *(f32x4*)((float*)C + base) = o0;
                *(f32x4*)((float*)C + base + 4) = o1;
            } else {
                *(bf16x8*)((bf16_t*)C + base) = cvt8(ov);
            }
        }
    }
}
template <int EPI>
__global__ __launch_bounds__(256) void gemm_bt(
    const bf16_t* A, const bf16_t* Bt, const float* bias, const void* res,
    const float* gamma, void* C, const int* flag,
    int arow0, int rrow0, int N, int K) {
    __shared__ __align__(16) bf16_t LDS[6][4096];   // 48 KiB: A0-2, B0-2
    if constexpr (EPI == 2) {
        if (*flag) {
            gemm_body<EPI, true>(LDS, A, Bt, bias, res, gamma, C, arow0, rrow0, N, K);
            return;
        }
    }
    gemm_body<EPI, false>(LDS, A, Bt, bias, res, gamma, C, arow0, rrow0, N, K);
}

// ---- windowed attention (reads pre-normalized bf16 xh; gq/bq f32) ----
// plane >= 0: per-plane mode, grid = 1024, kv/outc plane-local.
// plane < 0 : full-batch mode, grid = 8192, plane from blockIdx, kv/outc global.
__global__ __launch_bounds__(256) void attn_win(
    const bf16_t* xh, const float* gq, const float* bq,
    const bf16_t* kv, bf16_t* outc, int plane) {
    __shared__ __align__(16) char smem[62464];
    bf16_t(*Ql)[72] = (bf16_t(*)[72])smem;            // 64x72  (9216 B)
    bf16_t(*Kl)[72] = (bf16_t(*)[72])(smem + 9216);   // 192x72 (27648 B)
    bf16_t(*Pl)[200] = (bf16_t(*)[200])smem;          // 64x200 overlaps Ql/Kl (dead)
    bf16_t(*Vt)[200] = (bf16_t(*)[200])(smem + 36864);// 64x200, Vt[d][key]

    int blk = xcd_swz(blockIdx.x, gridDim.x);
    bool full = (plane < 0);
    if (full) { plane = blk >> 10; blk &= 1023; }
    int wl = blk >> 3, h = blk & 7;     // window-in-plane, head
    int i = wl;
    int t = threadIdx.x, wave = t >> 6, lane = t & 63, q = lane >> 4, li = lane & 15;
    size_t qg = (size_t)plane * PTOK + (size_t)wl * 64;   // global token base
    size_t ob = full ? qg : (size_t)wl * 64;              // output token base
    const bf16_t* kvp = full ? kv + (size_t)plane * PTOK * 1024 : kv;

    // stage Q (64x64): xh * g_q + b_q
#pragma unroll
    for (int l = t; l < 512; l += 256) {
        int row = l >> 3, seg = l & 7;
        f32x8 xv = load8f<false>(xh, (qg + row) * 512 + h * 64 + seg * 8);
        f32x8 gv = load8f<true>(gq, h * 64 + seg * 8);
        f32x8 bv = load8f<true>(bq, h * 64 + seg * 8);
        f32x8 w;
#pragma unroll
        for (int j = 0; j < 8; j++) w[j] = xv[j] * gv[j] + bv[j];
        *(bf16x8*)&Ql[row][seg * 8] = cvt8(w);
    }
    // stage K (192x64) and V transposed (Vt[d][key]); kvp is plane-local
#pragma unroll
    for (int l = t; l < 1536; l += 256) {
        int row = l >> 3, seg = l & 7;
        int nb = i + (row >> 6) - 1;
        nb = nb < 0 ? 0 : (nb > SWIN - 1 ? SWIN - 1 : nb);
        size_t tok = (size_t)nb * 64 + (row & 63);
        *(bf16x8*)&Kl[row][seg * 8] =
            *(const bf16x8*)&kvp[tok * 1024 + h * 64 + seg * 8];
        bf16x8 vv = *(const bf16x8*)&kvp[tok * 1024 + 512 + h * 64 + seg * 8];
#pragma unroll
        for (int j = 0; j < 8; j++) Vt[seg * 8 + j][row] = vv[j];
    }
    __syncthreads();

    int rm = wave * 16;
    const f32x4 fzero = {0.f, 0.f, 0.f, 0.f};
    f32x4 sc[12];
#pragma unroll
    for (int nt = 0; nt < 12; nt++) sc[nt] = fzero;
#pragma unroll
    for (int ks = 0; ks < 2; ks++) {
        bf16x8 aq = *(const bf16x8*)&Ql[rm + li][ks * 32 + q * 8];
#pragma unroll
        for (int nt = 0; nt < 12; nt++) {
            bf16x8 bk = *(const bf16x8*)&Kl[16 * nt + li][ks * 32 + q * 8];
            sc[nt] = mfma16(aq, bk, sc[nt]);
        }
    }
    // mask + softmax (row q*4+r, key = 16*nt+li)
    bool v0 = (i > 0), v2 = (i < SWIN - 1);
    float mx[4] = {-3e38f, -3e38f, -3e38f, -3e38f};
#pragma unroll
    for (int nt = 0; nt < 12; nt++) {
        bool valid = (nt < 4) ? v0 : ((nt >= 8) ? v2 : true);
#pragma unroll
        for (int r = 0; r < 4; r++) {
            float sv = valid ? sc[nt][r] * 0.125f : -3e38f;
            sc[nt][r] = sv;
            mx[r] = fmaxf(mx[r], sv);
        }
    }
#pragma unroll
    for (int r = 0; r < 4; r++)
#pragma unroll
        for (int msk = 1; msk < 16; msk <<= 1)
            mx[r] = fmaxf(mx[r], __shfl_xor(mx[r], msk));
    float lsum[4] = {0.f, 0.f, 0.f, 0.f};
#pragma unroll
    for (int nt = 0; nt < 12; nt++)
#pragma unroll
        for (int r = 0; r < 4; r++) {
            float e = __expf(sc[nt][r] - mx[r]);
            sc[nt][r] = e;
            lsum[r] += e;
        }
#pragma unroll
    for (int r = 0; r < 4; r++)
#pragma unroll
        for (int msk = 1; msk < 16; msk <<= 1)
            lsum[r] += __shfl_xor(lsum[r], msk);

    __syncthreads();  // all waves done with Ql/Kl before Pl overwrites
#pragma unroll
    for (int nt = 0; nt < 12; nt++)
#pragma unroll
        for (int r = 0; r < 4; r++)
            Pl[rm + q * 4 + r][16 * nt + li] = (bf16_t)sc[nt][r];
    __syncthreads();

    f32x4 o[4];
#pragma unroll
    for (int nt = 0; nt < 4; nt++) o[nt] = fzero;
#pragma unroll
    for (int ks = 0; ks < 6; ks++) {
        bf16x8 ap = *(const bf16x8*)&Pl[rm + li][ks * 32 + q * 8];
#pragma unroll
        for (int nt = 0; nt < 4; nt++) {
            bf16x8 bv = *(const bf16x8*)&Vt[16 * nt + li][ks * 32 + q * 8];
            o[nt] = mfma16(ap, bv, o[nt]);
        }
    }
#pragma unroll
    for (int r = 0; r < 4; r++) {
        float inv = 1.f / lsum[r];
        size_t tokr = ob + rm + q * 4 + r;
#pragma unroll
        for (int nt = 0; nt < 4; nt++)
            outc[tokr * 512 + h * 64 + 16 * nt + li] = (bf16_t)(o[nt][r] * inv);
    }
}

extern "C" void kernel_launch(void* const* d_in, const int* in_sizes, int n_in,
                              void* d_out, int out_size, void* d_ws, size_t ws_size,
                              hipStream_t stream) {
    const void* x      = d_in[0];
    const void* ln_q_g = d_in[1];
    const void* ln_q_b = d_in[2];
    const void* ln_kv_g= d_in[3];
    const void* ln_kv_b= d_in[4];
    const void* W_kv   = d_in[5];
    const void* b_kv   = d_in[6];
    const void* W_o    = d_in[7];
    const void* b_o    = d_in[8];
    const void* gamma  = d_in[9];
    const void* ln_m_g = d_in[10];
    const void* ln_m_b = d_in[11];
    const void* W_emb  = d_in[12];
    const void* b_emb  = d_in[13];
    const void* W1     = d_in[14];
    const void* b1     = d_in[15];
    const void* W2     = d_in[16];
    const void* b2     = d_in[17];
    const void* gm_mlp = d_in[18];
    char* ws = (char*)d_ws;

    // fixed small region
    bf16_t* Wt_kv  = (bf16_t*)(ws);                     // [1024,512]  1 MiB
    bf16_t* Wt_o   = (bf16_t*)(ws + (1u << 20));        // [512,512]
    bf16_t* Wt_emb = (bf16_t*)(ws + 1572864);           // [512,512]
    bf16_t* Wt_1   = (bf16_t*)(ws + (2u << 20));        // [1024,512]
    bf16_t* Wt_2   = (bf16_t*)(ws + (3u << 20));        // [512,1024]
    float*  smallF = (float*)(ws + (4u << 20));         // 16 KiB f32 consts
    float*  bkv_f  = (float*)(ws + (4u << 20) + 16384); // [1024]
    float*  bemb_f = (float*)(ws + (4u << 20) + 20480); // [512]
    int*    flag   = (int*)(ws + (5u << 20));
    float*  gamma_f = smallF;
    float*  gm_f    = smallF + 512;
    float*  gq_f    = smallF + 1024;
    float*  bq_f    = smallF + 1536;
    float*  bo_f    = smallF + 2048;
    float*  b1_f    = smallF + 2560;
    float*  b2_f    = smallF + 3584;

    detect_dtype<<<1, 256, 0, stream>>>(x, flag);
    // transposed (optionally ln-gain-folded) bf16 weights
    transpose_conv<<<2048, 256, 0, stream>>>(W_kv, ln_kv_g, Wt_kv, 512, 1024, flag);
    transpose_conv<<<1024, 256, 0, stream>>>(W_o, nullptr, Wt_o, 512, 512, flag);
    transpose_conv<<<1024, 256, 0, stream>>>(W_emb, ln_m_g, Wt_emb, 512, 512, flag);
    transpose_conv<<<2048, 256, 0, stream>>>(W1, nullptr, Wt_1, 512, 1024, flag);
    transpose_conv<<<2048, 256, 0, stream>>>(W2, nullptr, Wt_2, 1024, 512, flag);
    conv_all<<<16, 256, 0, stream>>>(gamma, gm_mlp, ln_q_g, ln_q_b, b_o, b1, b2,
                                     smallF, flag);
    fold_bias<<<4, 256, 0, stream>>>(W_kv, ln_kv_b, b_kv, bkv_f, 512, 1024, flag);
    fold_bias<<<2, 256, 0, stream>>>(W_emb, ln_m_b, b_emb, bemb_f, 512, 512, flag);

    bool big = ws_size >= ((size_t)480 << 20);
    bf16_t* xh  = (bf16_t*)(ws + ((size_t)8 << 20));    // [65536,512] 64 MiB
    bf16_t* xh2 = (bf16_t*)(ws + ((size_t)72 << 20));   // [65536,512] 64 MiB

    // LN-normalize x -> xh (bf16)
    ln_norm<<<NTOKENS / 4, 256, 0, stream>>>(x, xh, flag);

    if (big) {
        bf16_t* kvC   = (bf16_t*)(ws + ((size_t)136 << 20));  // [65536,1024] 128 MiB
        bf16_t* attnC = (bf16_t*)(ws + ((size_t)264 << 20));  // [65536,512]   64 MiB
        bf16_t* h1C   = kvC;                                  // reuse
        bf16_t* h2C   = (bf16_t*)(ws + ((size_t)328 << 20));  // [65536,1024] 128 MiB

        gemm_bt<0><<<dim3(8, 512), 256, 0, stream>>>(
            xh, Wt_kv, bkv_f, nullptr, nullptr, kvC, flag, 0, 0, 1024, 512);
        attn_win<<<8192, 256, 0, stream>>>(xh, gq_f, bq_f, kvC, attnC, -1);
        gemm_bt<2><<<dim3(4, 512), 256, 0, stream>>>(
            attnC, Wt_o, bo_f, x, gamma_f, d_out, flag, 0, 0, 512, 512);
        ln_norm<<<NTOKENS / 4, 256, 0, stream>>>(d_out, xh2, flag);
        gemm_bt<0><<<dim3(4, 512), 256, 0, stream>>>(
            xh2, Wt_emb, bemb_f, nullptr, nullptr, h1C, flag, 0, 0, 512, 512);
        gemm_bt<1><<<dim3(8, 512), 256, 0, stream>>>(
            h1C, Wt_1, b1_f, nullptr, nullptr, h2C, flag, 0, 0, 1024, 512);
        gemm_bt<2><<<dim3(4, 512), 256, 0, stream>>>(
            h2C, Wt_2, b2_f, d_out, gm_f, d_out, flag, 0, 0, 512, 1024);
        return;
    }

    // ---- fallback: per-plane chunked path (needs ~160 MiB) ----
    bf16_t* kvC16 = (bf16_t*)(ws + ((size_t)136 << 20));  // [8192,1024] 16 MiB
    bf16_t* h1C8  = (bf16_t*)(ws + ((size_t)136 << 20));  // reuse (MLP phase)
    bf16_t* h2C16 = (bf16_t*)(ws + ((size_t)144 << 20));  // [8192,1024] 16 MiB
    bf16_t* attnC8= (bf16_t*)(ws + ((size_t)152 << 20));  // [8192,512]   8 MiB

    for (int p = 0; p < PLANES; p++) {
        int row0 = p * PTOK;
        gemm_bt<0><<<dim3(8, 64), 256, 0, stream>>>(
            xh, Wt_kv, bkv_f, nullptr, nullptr, kvC16, flag, row0, 0, 1024, 512);
        attn_win<<<1024, 256, 0, stream>>>(xh, gq_f, bq_f, kvC16, attnC8, p);
        gemm_bt<2><<<dim3(4, 64), 256, 0, stream>>>(
            attnC8, Wt_o, bo_f, x, gamma_f, d_out, flag, 0, row0, 512, 512);
    }
    ln_norm<<<NTOKENS / 4, 256, 0, stream>>>(d_out, xh2, flag);
    for (int p = 0; p < PLANES; p++) {
        int row0 = p * PTOK;
        gemm_bt<0><<<dim3(4, 64), 256, 0, stream>>>(
            xh2, Wt_emb, bemb_f, nullptr, nullptr, h1C8, flag, row0, 0, 512, 512);
        gemm_bt<1><<<dim3(8, 64), 256, 0, stream>>>(
            h1C8, Wt_1, b1_f, nullptr, nullptr, h2C16, flag, 0, 0, 1024, 512);
        gemm_bt<2><<<dim3(4, 64), 256, 0, stream>>>(
            h2C16, Wt_2, b2_f, d_out, gm_f, d_out, flag, 0, row0, 512, 1024);
    }
}

// Round 5
// 904.113 us; speedup vs baseline: 1.5194x; 1.2548x over previous
//
#include <hip/hip_runtime.h>

typedef __bf16 bf16_t;
typedef __bf16 bf16x8 __attribute__((ext_vector_type(8)));
typedef float f32x4 __attribute__((ext_vector_type(4)));
typedef float f32x8 __attribute__((ext_vector_type(8)));

#define NTOKENS 65536   // B*V*T*NTOK = 1*2*4*8192
#define PLANES 8        // b*v*t planes, 8192 tokens each
#define PTOK 8192
#define SWIN 128        // windows per plane

static __device__ __forceinline__ f32x4 mfma16(bf16x8 a, bf16x8 b, f32x4 c) {
    return __builtin_amdgcn_mfma_f32_16x16x32_bf16(a, b, c, 0, 0, 0);
}

// async global->LDS, 16B per lane; lds dest must be wave-uniform base
static __device__ __forceinline__ void gld16(const void* g, void* l) {
    __builtin_amdgcn_global_load_lds(
        (const __attribute__((address_space(1))) void*)g,
        (__attribute__((address_space(3))) void*)l, 16, 0, 0);
}

// bijective XCD-chunk swizzle (nwg must be divisible by 8)
static __device__ __forceinline__ int xcd_swz(int lin, int nwg) {
    return (lin & 7) * (nwg >> 3) + (lin >> 3);
}

// ---- dtype-generic accessors (F32: buffer is float, else bf16) ----
template <bool F32>
static __device__ __forceinline__ f32x8 load8f(const void* p, size_t i) {
    f32x8 r;
    if (F32) {
        const f32x4* q = (const f32x4*)((const float*)p + i);
        f32x4 a = q[0], b = q[1];
#pragma unroll
        for (int j = 0; j < 4; j++) { r[j] = a[j]; r[4 + j] = b[j]; }
    } else {
        bf16x8 v = *(const bf16x8*)((const bf16_t*)p + i);
#pragma unroll
        for (int j = 0; j < 8; j++) r[j] = (float)v[j];
    }
    return r;
}
template <bool F32>
static __device__ __forceinline__ float ld1f(const void* p, size_t i) {
    return F32 ? ((const float*)p)[i] : (float)((const bf16_t*)p)[i];
}
template <bool F32>
static __device__ __forceinline__ void st1f(void* p, size_t i, float v) {
    if (F32) ((float*)p)[i] = v; else ((bf16_t*)p)[i] = (bf16_t)v;
}
static __device__ __forceinline__ bf16x8 cvt8(f32x8 f) {
    bf16x8 w;
#pragma unroll
    for (int j = 0; j < 8; j++) w[j] = (bf16_t)f[j];
    return w;
}

// ---- dtype detector: sample even-indexed uint16s of x ----
__global__ void detect_dtype(const void* x, int* flag) {
    __shared__ int cnt[256];
    int t = threadIdx.x;
    const unsigned short* u = (const unsigned short*)x;
    int c = 0;
    for (int i = t; i < 4096; i += 256) {
        int e = (u[2 * i] >> 7) & 0xFF;
        c += (e >= 64 && e <= 140) ? 1 : 0;
    }
    cnt[t] = c;
    __syncthreads();
    for (int s = 128; s > 0; s >>= 1) {
        if (t < s) cnt[t] += cnt[t + s];
        __syncthreads();
    }
    if (t == 0) flag[0] = (cnt[0] < 3072) ? 1 : 0;
}

// ---- weight transpose+convert (+optional per-k gain): dst[n][k]=g[k]*src[k][n]
__global__ void transpose_conv(const void* src, const void* gain, bf16_t* dst,
                               int K, int N, const int* flag) {
    int idx = blockIdx.x * 256 + threadIdx.x;
    if (idx >= K * N) return;
    int n = idx % N, k = idx / N;
    bool f = *flag;
    float v = f ? ((const float*)src)[(size_t)k * N + n]
                : (float)((const bf16_t*)src)[(size_t)k * N + n];
    if (gain) {
        float g = f ? ((const float*)gain)[k] : (float)((const bf16_t*)gain)[k];
        v *= g;
    }
    dst[(size_t)n * K + k] = (bf16_t)v;
}

// ---- folded bias: out[n] = b[n] + sum_k bln[k]*W[k][n]  (f32 out) ----
// one wave per output column; lanes stride K, shuffle-tree reduce.
__global__ __launch_bounds__(256) void fold_bias(
    const void* W, const void* bln, const void* b,
    float* out, int K, int N, const int* flag) {
    int wave = threadIdx.x >> 6, lane = threadIdx.x & 63;
    int n = blockIdx.x * 4 + wave;
    if (n >= N) return;
    bool f = *flag;
    float s = 0.f;
    for (int k = lane; k < K; k += 64) {
        float bl = f ? ((const float*)bln)[k] : (float)((const bf16_t*)bln)[k];
        float w  = f ? ((const float*)W)[(size_t)k * N + n]
                     : (float)((const bf16_t*)W)[(size_t)k * N + n];
        s += bl * w;
    }
#pragma unroll
    for (int off = 32; off > 0; off >>= 1) s += __shfl_xor(s, off);
    if (lane == 0) {
        float bb = f ? ((const float*)b)[n] : (float)((const bf16_t*)b)[n];
        out[n] = s + bb;
    }
}

// ---- batch convert small vectors to f32 (one launch) ----
// layout in out: gamma[512] gm[512] gq[512] bq[512] bo[512] b1[1024] b2[512]
__global__ void conv_all(const void* gamma, const void* gm, const void* gq,
                         const void* bq, const void* bo, const void* b1,
                         const void* b2, float* out, const int* flag) {
    int idx = blockIdx.x * 256 + threadIdx.x;  // 0..4095
    bool f = *flag;
    const void* src; int off;
    if      (idx < 512)  { src = gamma; off = idx; }
    else if (idx < 1024) { src = gm;    off = idx - 512; }
    else if (idx < 1536) { src = gq;    off = idx - 1024; }
    else if (idx < 2048) { src = bq;    off = idx - 1536; }
    else if (idx < 2560) { src = bo;    off = idx - 2048; }
    else if (idx < 3584) { src = b1;    off = idx - 2560; }
    else                 { src = b2;    off = idx - 3584; }
    out[idx] = f ? ((const float*)src)[off] : (float)((const bf16_t*)src)[off];
}

// ---- fused LN-normalize: xh[row] = (x[row]-mean)*rstd  (bf16 out) ----
template <bool F32>
static __device__ __forceinline__ void ln_norm_body(const void* x, bf16_t* xh) {
    int wave = threadIdx.x >> 6, lane = threadIdx.x & 63;
    size_t row = (size_t)blockIdx.x * 4 + wave;
    f32x8 f = load8f<F32>(x, row * 512 + lane * 8);
    float s = 0.f, s2 = 0.f;
#pragma unroll
    for (int j = 0; j < 8; j++) { s += f[j]; s2 += f[j] * f[j]; }
#pragma unroll
    for (int off = 32; off > 0; off >>= 1) { s += __shfl_xor(s, off); s2 += __shfl_xor(s2, off); }
    float m = s * (1.f / 512.f);
    float var = s2 * (1.f / 512.f) - m * m;
    float r = 1.f / sqrtf(var + 1e-5f);
    bf16x8 o;
#pragma unroll
    for (int j = 0; j < 8; j++) o[j] = (bf16_t)((f[j] - m) * r);
    *(bf16x8*)(xh + row * 512 + lane * 8) = o;
}
__global__ __launch_bounds__(256) void ln_norm(const void* x, bf16_t* xh,
                                               const int* flag) {
    if (*flag) ln_norm_body<true>(x, xh);
    else       ln_norm_body<false>(x, xh);
}

// ---- pure bf16 GEMM: C = epi(A[M,K] @ Bt[N,K]^T + bias) ----
// EPI 0: +bias   EPI 1: gelu(+bias)   EPI 2: res + gamma*(+bias) (res/C dtype F32)
// 3-deep prefetch pipeline with counted vmcnt across raw barriers (T4):
// prologue stages tiles 0,1,2; steady phase waits vmcnt(8) (2 tiles stay in
// flight across both barriers), computes tile t, then after the read-release
// barrier stages tile t+3 into the buffer just consumed. Drain to 0 only at
// the tail. LDS tiles slot-XOR-swizzled on BOTH the global_load_lds source
// address and the ds_read address (rule #21):
// tile row r (0..127), 16-B slot s' (0..3) holds global slot s = s'^((r>>1)&3).
template <int EPI, bool F32>
static __device__ __forceinline__ void gemm_body(
    bf16_t (*LDS)[4096],
    const bf16_t* A, const bf16_t* Bt, const float* bias, const void* res,
    const float* gamma, void* C, int arow0, int rrow0, int N, int K) {
    int t = threadIdx.x;
    int gx = gridDim.x;
    int nwg = gx * gridDim.y;
    int lin = blockIdx.y * gx + blockIdx.x;
    int s = xcd_swz(lin, nwg);
    int m0 = (s / gx) * 128, n0 = (s % gx) * 128;
    int wave = t >> 6, lane = t & 63, q = lane >> 4, li = lane & 15;
    int wm = (wave >> 1) * 64, wn = (wave & 1) * 64;
    const f32x4 fzero = {0.f, 0.f, 0.f, 0.f};
    f32x4 acc[4][4];
#pragma unroll
    for (int i = 0; i < 4; i++)
#pragma unroll
        for (int n = 0; n < 4; n++) acc[i][n] = fzero;

    // staging: wave w, lane ln writes LDS bytes {w*1024 + ln*16} (+4096 for
    // rows 64..127) -> row = [64h+] w*16 + ln/4, slot s' = ln&3. Source must
    // be global slot s'^swz(row).  ((row+64)>>1)&3 == (row>>1)&3 -> one scol.
    int srow = wave * 16 + (lane >> 2);
    int scol = (((lane & 3) ^ ((srow >> 1) & 3)) << 3);
    const bf16_t* gA = A + (size_t)(arow0 + m0 + srow) * K + scol;
    const bf16_t* gB = Bt + (size_t)(n0 + srow) * K + scol;
    const size_t half = (size_t)64 * K;

    // swizzled LDS read offsets (elem units)
    int offA[4], offB[4];
#pragma unroll
    for (int i = 0; i < 4; i++) {
        int Ra = wm + 16 * i + li;
        offA[i] = Ra * 32 + ((q ^ ((Ra >> 1) & 3)) << 3);
        int Rb = wn + 16 * i + li;
        offB[i] = Rb * 32 + ((q ^ ((Rb >> 1) & 3)) << 3);
    }

    auto STAGE = [&](int k0, int c) {
        bf16_t* pa = &LDS[c][wave * 512];
        bf16_t* pb = &LDS[3 + c][wave * 512];
        gld16(gA + k0, pa);
        gld16(gA + half + k0, pa + 2048);
        gld16(gB + k0, pb);
        gld16(gB + half + k0, pb + 2048);
    };
    auto COMPUTE = [&](int c) {
        bf16x8 af[4], bfr[4];
#pragma unroll
        for (int i = 0; i < 4; i++) af[i] = *(const bf16x8*)&LDS[c][offA[i]];
#pragma unroll
        for (int n = 0; n < 4; n++) bfr[n] = *(const bf16x8*)&LDS[3 + c][offB[n]];
#pragma unroll
        for (int i = 0; i < 4; i++)
#pragma unroll
            for (int n = 0; n < 4; n++) acc[i][n] = mfma16(af[i], bfr[n], acc[i][n]);
    };

    int nt = K >> 5;   // 16 or 32
    STAGE(0, 0);
    STAGE(32, 1);
    STAGE(64, 2);
    int c = 0;
    for (int tt = 0; tt < nt; tt++) {
        if (tt + 2 < nt)      asm volatile("s_waitcnt vmcnt(8)" ::: "memory");
        else if (tt + 1 < nt) asm volatile("s_waitcnt vmcnt(4)" ::: "memory");
        else                  asm volatile("s_waitcnt vmcnt(0)" ::: "memory");
        __builtin_amdgcn_s_barrier();
        __builtin_amdgcn_sched_barrier(0);
        COMPUTE(c);
        __builtin_amdgcn_sched_barrier(0);
        asm volatile("s_waitcnt lgkmcnt(0)" ::: "memory");
        __builtin_amdgcn_s_barrier();
        __builtin_amdgcn_sched_barrier(0);
        if (tt + 3 < nt) STAGE((tt + 3) << 5, c);
        c = (c == 2) ? 0 : c + 1;
    }

    if (EPI <= 1) {
        // coalesced epilogue: wave-private 64x64 bf16 chunk in LDS, slot-XOR
        // swizzled (slot' = slot ^ (row&7)); stores become 128-B full lines.
        bf16_t* ch = &LDS[wave][0];
#pragma unroll
        for (int n = 0; n < 4; n++) {
            float bv = bias[n0 + wn + 16 * n + li];
#pragma unroll
            for (int i = 0; i < 4; i++) {
#pragma unroll
                for (int r = 0; r < 4; r++) {
                    float v = acc[i][n][r] + bv;
                    if (EPI == 1) {
                        float u = v;
                        v = 0.5f * u * (1.f + tanhf(0.7978845608028654f * (u + 0.044715f * u * u * u)));
                    }
                    int row = 16 * i + q * 4 + r;
                    int sl = (((2 * n + (li >> 3)) ^ (row & 7)) << 3) + (li & 7);
                    ch[row * 64 + sl] = (bf16_t)v;
                }
            }
        }
        asm volatile("s_waitcnt lgkmcnt(0)" ::: "memory");
        __builtin_amdgcn_sched_barrier(0);
#pragma unroll
        for (int p = 0; p < 8; p++) {
            int rl = p * 8 + (lane >> 3);
            int sl = (((lane & 7) ^ (rl & 7)) << 3);
            bf16x8 v8 = *(const bf16x8*)&ch[rl * 64 + sl];
            *(bf16x8*)((bf16_t*)C + (size_t)(m0 + wm + rl) * N + n0 + wn +
                       ((lane & 7) << 3)) = v8;
        }
    } else {
        // EPI 2: residual epilogue, also via LDS chunk for coalesced I/O.
        // chunk holds raw acc (bias/gamma applied at read time, per-column).
        bf16_t* ch = &LDS[wave][0];
#pragma unroll
        for (int n = 0; n < 4; n++) {
#pragma unroll
            for (int i = 0; i < 4; i++) {
#pragma unroll
                for (int r = 0; r < 4; r++) {
                    int row = 16 * i + q * 4 + r;
                    int sl = (((2 * n + (li >> 3)) ^ (row & 7)) << 3) + (li & 7);
                    ch[row * 64 + sl] = (bf16_t)acc[i][n][r];
                }
            }
        }
        asm volatile("s_waitcnt lgkmcnt(0)" ::: "memory");
        __builtin_amdgcn_sched_barrier(0);
        int colb = n0 + wn + ((lane & 7) << 3);
        f32x8 gv8 = load8f<true>(gamma, colb);
        f32x8 bv8 = load8f<true>(bias, colb);
#pragma unroll
        for (int p = 0; p < 8; p++) {
            int rl = p * 8 + (lane >> 3);
            int sl = (((lane & 7) ^ (rl & 7)) << 3);
            bf16x8 v8 = *(const bf16x8*)&ch[rl * 64 + sl];
            size_t base = (size_t)(rrow0 + m0 + wm + rl) * N + colb;
            f32x8 rv = load8f<F32>(res, base);
            f32x8 ov;
#pragma unroll
            for (int j = 0; j < 8; j++)
                ov[j] = rv[j] + gv8[j] * ((float)v8[j] + bv8[j]);
            if (F32) {
                f32x4 o0, o1;
#pragma unroll
                for (int j = 0; j < 4; j++) { o0[j] = ov[j]; o1[j] = ov[4 + j]; }
                *(f32x4*)((float*)C + base) = o0;
                *(f32x4*)((float*)C + base + 4) = o1;
            } else {
                *(bf16x8*)((bf16_t*)C + base) = cvt8(ov);
            }
        }
    }
}
template <int EPI>
__global__ __launch_bounds__(256) void gemm_bt(
    const bf16_t* A, const bf16_t* Bt, const float* bias, const void* res,
    const float* gamma, void* C, const int* flag,
    int arow0, int rrow0, int N, int K) {
    __shared__ __align__(16) bf16_t LDS[6][4096];   // 48 KiB: A0-2, B0-2
    if constexpr (EPI == 2) {
        if (*flag) {
            gemm_body<EPI, true>(LDS, A, Bt, bias, res, gamma, C, arow0, rrow0, N, K);
            return;
        }
    }
    gemm_body<EPI, false>(LDS, A, Bt, bias, res, gamma, C, arow0, rrow0, N, K);
}

// ---- windowed attention (reads pre-normalized bf16 xh; gq/bq f32) ----
// plane >= 0: per-plane mode, grid = 1024, kv/outc plane-local.
// plane < 0 : full-batch mode, grid = 8192, plane from blockIdx, kv/outc global.
__global__ __launch_bounds__(256) void attn_win(
    const bf16_t* xh, const float* gq, const float* bq,
    const bf16_t* kv, bf16_t* outc, int plane) {
    __shared__ __align__(16) char smem[62464];
    bf16_t(*Ql)[72] = (bf16_t(*)[72])smem;            // 64x72  (9216 B)
    bf16_t(*Kl)[72] = (bf16_t(*)[72])(smem + 9216);   // 192x72 (27648 B)
    bf16_t(*Pl)[200] = (bf16_t(*)[200])smem;          // 64x200 overlaps Ql/Kl (dead)
    bf16_t(*Vt)[200] = (bf16_t(*)[200])(smem + 36864);// 64x200, Vt[d][key]

    int blk = xcd_swz(blockIdx.x, gridDim.x);
    bool full = (plane < 0);
    if (full) { plane = blk >> 10; blk &= 1023; }
    int wl = blk >> 3, h = blk & 7;     // window-in-plane, head
    int i = wl;
    int t = threadIdx.x, wave = t >> 6, lane = t & 63, q = lane >> 4, li = lane & 15;
    size_t qg = (size_t)plane * PTOK + (size_t)wl * 64;   // global token base
    size_t ob = full ? qg : (size_t)wl * 64;              // output token base
    const bf16_t* kvp = full ? kv + (size_t)plane * PTOK * 1024 : kv;

    // stage Q (64x64): xh * g_q + b_q
#pragma unroll
    for (int l = t; l < 512; l += 256) {
        int row = l >> 3, seg = l & 7;
        f32x8 xv = load8f<false>(xh, (qg + row) * 512 + h * 64 + seg * 8);
        f32x8 gv = load8f<true>(gq, h * 64 + seg * 8);
        f32x8 bv = load8f<true>(bq, h * 64 + seg * 8);
        f32x8 w;
#pragma unroll
        for (int j = 0; j < 8; j++) w[j] = xv[j] * gv[j] + bv[j];
        *(bf16x8*)&Ql[row][seg * 8] = cvt8(w);
    }
    // stage K (192x64) and V transposed (Vt[d][key]); kvp is plane-local
#pragma unroll
    for (int l = t; l < 1536; l += 256) {
        int row = l >> 3, seg = l & 7;
        int nb = i + (row >> 6) - 1;
        nb = nb < 0 ? 0 : (nb > SWIN - 1 ? SWIN - 1 : nb);
        size_t tok = (size_t)nb * 64 + (row & 63);
        *(bf16x8*)&Kl[row][seg * 8] =
            *(const bf16x8*)&kvp[tok * 1024 + h * 64 + seg * 8];
        bf16x8 vv = *(const bf16x8*)&kvp[tok * 1024 + 512 + h * 64 + seg * 8];
#pragma unroll
        for (int j = 0; j < 8; j++) Vt[seg * 8 + j][row] = vv[j];
    }
    __syncthreads();

    int rm = wave * 16;
    const f32x4 fzero = {0.f, 0.f, 0.f, 0.f};
    f32x4 sc[12];
#pragma unroll
    for (int nt = 0; nt < 12; nt++) sc[nt] = fzero;
#pragma unroll
    for (int ks = 0; ks < 2; ks++) {
        bf16x8 aq = *(const bf16x8*)&Ql[rm + li][ks * 32 + q * 8];
#pragma unroll
        for (int nt = 0; nt < 12; nt++) {
            bf16x8 bk = *(const bf16x8*)&Kl[16 * nt + li][ks * 32 + q * 8];
            sc[nt] = mfma16(aq, bk, sc[nt]);
        }
    }
    // mask + softmax (row q*4+r, key = 16*nt+li)
    bool v0 = (i > 0), v2 = (i < SWIN - 1);
    float mx[4] = {-3e38f, -3e38f, -3e38f, -3e38f};
#pragma unroll
    for (int nt = 0; nt < 12; nt++) {
        bool valid = (nt < 4) ? v0 : ((nt >= 8) ? v2 : true);
#pragma unroll
        for (int r = 0; r < 4; r++) {
            float sv = valid ? sc[nt][r] * 0.125f : -3e38f;
            sc[nt][r] = sv;
            mx[r] = fmaxf(mx[r], sv);
        }
    }
#pragma unroll
    for (int r = 0; r < 4; r++)
#pragma unroll
        for (int msk = 1; msk < 16; msk <<= 1)
            mx[r] = fmaxf(mx[r], __shfl_xor(mx[r], msk));
    float lsum[4] = {0.f, 0.f, 0.f, 0.f};
#pragma unroll
    for (int nt = 0; nt < 12; nt++)
#pragma unroll
        for (int r = 0; r < 4; r++) {
            float e = __expf(sc[nt][r] - mx[r]);
            sc[nt][r] = e;
            lsum[r] += e;
        }
#pragma unroll
    for (int r = 0; r < 4; r++)
#pragma unroll
        for (int msk = 1; msk < 16; msk <<= 1)
            lsum[r] += __shfl_xor(lsum[r], msk);

    __syncthreads();  // all waves done with Ql/Kl before Pl overwrites
#pragma unroll
    for (int nt = 0; nt < 12; nt++)
#pragma unroll
        for (int r = 0; r < 4; r++)
            Pl[rm + q * 4 + r][16 * nt + li] = (bf16_t)sc[nt][r];
    __syncthreads();

    f32x4 o[4];
#pragma unroll
    for (int nt = 0; nt < 4; nt++) o[nt] = fzero;
#pragma unroll
    for (int ks = 0; ks < 6; ks++) {
        bf16x8 ap = *(const bf16x8*)&Pl[rm + li][ks * 32 + q * 8];
#pragma unroll
        for (int nt = 0; nt < 4; nt++) {
            bf16x8 bv = *(const bf16x8*)&Vt[16 * nt + li][ks * 32 + q * 8];
            o[nt] = mfma16(ap, bv, o[nt]);
        }
    }
#pragma unroll
    for (int r = 0; r < 4; r++) {
        float inv = 1.f / lsum[r];
        size_t tokr = ob + rm + q * 4 + r;
#pragma unroll
        for (int nt = 0; nt < 4; nt++)
            outc[tokr * 512 + h * 64 + 16 * nt + li] = (bf16_t)(o[nt][r] * inv);
    }
}

extern "C" void kernel_launch(void* const* d_in, const int* in_sizes, int n_in,
                              void* d_out, int out_size, void* d_ws, size_t ws_size,
                              hipStream_t stream) {
    const void* x      = d_in[0];
    const void* ln_q_g = d_in[1];
    const void* ln_q_b = d_in[2];
    const void* ln_kv_g= d_in[3];
    const void* ln_kv_b= d_in[4];
    const void* W_kv   = d_in[5];
    const void* b_kv   = d_in[6];
    const void* W_o    = d_in[7];
    const void* b_o    = d_in[8];
    const void* gamma  = d_in[9];
    const void* ln_m_g = d_in[10];
    const void* ln_m_b = d_in[11];
    const void* W_emb  = d_in[12];
    const void* b_emb  = d_in[13];
    const void* W1     = d_in[14];
    const void* b1     = d_in[15];
    const void* W2     = d_in[16];
    const void* b2     = d_in[17];
    const void* gm_mlp = d_in[18];
    char* ws = (char*)d_ws;

    // fixed small region
    bf16_t* Wt_kv  = (bf16_t*)(ws);                     // [1024,512]  1 MiB
    bf16_t* Wt_o   = (bf16_t*)(ws + (1u << 20));        // [512,512]
    bf16_t* Wt_emb = (bf16_t*)(ws + 1572864);           // [512,512]
    bf16_t* Wt_1   = (bf16_t*)(ws + (2u << 20));        // [1024,512]
    bf16_t* Wt_2   = (bf16_t*)(ws + (3u << 20));        // [512,1024]
    float*  smallF = (float*)(ws + (4u << 20));         // 16 KiB f32 consts
    float*  bkv_f  = (float*)(ws + (4u << 20) + 16384); // [1024]
    float*  bemb_f = (float*)(ws + (4u << 20) + 20480); // [512]
    int*    flag   = (int*)(ws + (5u << 20));
    float*  gamma_f = smallF;
    float*  gm_f    = smallF + 512;
    float*  gq_f    = smallF + 1024;
    float*  bq_f    = smallF + 1536;
    float*  bo_f    = smallF + 2048;
    float*  b1_f    = smallF + 2560;
    float*  b2_f    = smallF + 3584;

    detect_dtype<<<1, 256, 0, stream>>>(x, flag);
    // transposed (optionally ln-gain-folded) bf16 weights
    transpose_conv<<<2048, 256, 0, stream>>>(W_kv, ln_kv_g, Wt_kv, 512, 1024, flag);
    transpose_conv<<<1024, 256, 0, stream>>>(W_o, nullptr, Wt_o, 512, 512, flag);
    transpose_conv<<<1024, 256, 0, stream>>>(W_emb, ln_m_g, Wt_emb, 512, 512, flag);
    transpose_conv<<<2048, 256, 0, stream>>>(W1, nullptr, Wt_1, 512, 1024, flag);
    transpose_conv<<<2048, 256, 0, stream>>>(W2, nullptr, Wt_2, 1024, 512, flag);
    conv_all<<<16, 256, 0, stream>>>(gamma, gm_mlp, ln_q_g, ln_q_b, b_o, b1, b2,
                                     smallF, flag);
    fold_bias<<<256, 256, 0, stream>>>(W_kv, ln_kv_b, b_kv, bkv_f, 512, 1024, flag);
    fold_bias<<<128, 256, 0, stream>>>(W_emb, ln_m_b, b_emb, bemb_f, 512, 512, flag);

    bool big = ws_size >= ((size_t)480 << 20);
    bf16_t* xh  = (bf16_t*)(ws + ((size_t)8 << 20));    // [65536,512] 64 MiB
    bf16_t* xh2 = (bf16_t*)(ws + ((size_t)72 << 20));   // [65536,512] 64 MiB

    // LN-normalize x -> xh (bf16)
    ln_norm<<<NTOKENS / 4, 256, 0, stream>>>(x, xh, flag);

    if (big) {
        bf16_t* kvC   = (bf16_t*)(ws + ((size_t)136 << 20));  // [65536,1024] 128 MiB
        bf16_t* attnC = (bf16_t*)(ws + ((size_t)264 << 20));  // [65536,512]   64 MiB
        bf16_t* h1C   = kvC;                                  // reuse
        bf16_t* h2C   = (bf16_t*)(ws + ((size_t)328 << 20));  // [65536,1024] 128 MiB

        gemm_bt<0><<<dim3(8, 512), 256, 0, stream>>>(
            xh, Wt_kv, bkv_f, nullptr, nullptr, kvC, flag, 0, 0, 1024, 512);
        attn_win<<<8192, 256, 0, stream>>>(xh, gq_f, bq_f, kvC, attnC, -1);
        gemm_bt<2><<<dim3(4, 512), 256, 0, stream>>>(
            attnC, Wt_o, bo_f, x, gamma_f, d_out, flag, 0, 0, 512, 512);
        ln_norm<<<NTOKENS / 4, 256, 0, stream>>>(d_out, xh2, flag);
        gemm_bt<0><<<dim3(4, 512), 256, 0, stream>>>(
            xh2, Wt_emb, bemb_f, nullptr, nullptr, h1C, flag, 0, 0, 512, 512);
        gemm_bt<1><<<dim3(8, 512), 256, 0, stream>>>(
            h1C, Wt_1, b1_f, nullptr, nullptr, h2C, flag, 0, 0, 1024, 512);
        gemm_bt<2><<<dim3(4, 512), 256, 0, stream>>>(
            h2C, Wt_2, b2_f, d_out, gm_f, d_out, flag, 0, 0, 512, 1024);
        return;
    }

    // ---- fallback: per-plane chunked path (needs ~160 MiB) ----
    bf16_t* kvC16 = (bf16_t*)(ws + ((size_t)136 << 20));  // [8192,1024] 16 MiB
    bf16_t* h1C8  = (bf16_t*)(ws + ((size_t)136 << 20));  // reuse (MLP phase)
    bf16_t* h2C16 = (bf16_t*)(ws + ((size_t)144 << 20));  // [8192,1024] 16 MiB
    bf16_t* attnC8= (bf16_t*)(ws + ((size_t)152 << 20));  // [8192,512]   8 MiB

    for (int p = 0; p < PLANES; p++) {
        int row0 = p * PTOK;
        gemm_bt<0><<<dim3(8, 64), 256, 0, stream>>>(
            xh, Wt_kv, bkv_f, nullptr, nullptr, kvC16, flag, row0, 0, 1024, 512);
        attn_win<<<1024, 256, 0, stream>>>(xh, gq_f, bq_f, kvC16, attnC8, p);
        gemm_bt<2><<<dim3(4, 64), 256, 0, stream>>>(
            attnC8, Wt_o, bo_f, x, gamma_f, d_out, flag, 0, row0, 512, 512);
    }
    ln_norm<<<NTOKENS / 4, 256, 0, stream>>>(d_out, xh2, flag);
    for (int p = 0; p < PLANES; p++) {
        int row0 = p * PTOK;
        gemm_bt<0><<<dim3(4, 64), 256, 0, stream>>>(
            xh2, Wt_emb, bemb_f, nullptr, nullptr, h1C8, flag, row0, 0, 512, 512);
        gemm_bt<1><<<dim3(8, 64), 256, 0, stream>>>(
            h1C8, Wt_1, b1_f, nullptr, nullptr, h2C16, flag, 0, 0, 1024, 512);
        gemm_bt<2><<<dim3(4, 64), 256, 0, stream>>>(
            h2C16, Wt_2, b2_f, d_out, gm_f, d_out, flag, 0, row0, 512, 1024);
    }
}